// Round 10
// baseline (699.597 us; speedup 1.0000x reference)
//
#include <hip/hip_runtime.h>

#define CC   64
#define SHOT 16
#define DD   320
#define ND   1008            // (CC-1)*SHOT
#define MS   (CC * SHOT)     // 1024
#define MD   (CC * ND)       // 64512
#define MT   (MD + MS)       // 65536 = 512*128
#define LN_EPS 1e-5f

typedef __attribute__((ext_vector_type(8)))  short short8;    // 8 bf16 = 4 VGPR
typedef __attribute__((ext_vector_type(4)))  float floatx4;
typedef __attribute__((ext_vector_type(4)))  int i32x4;

__device__ __forceinline__ unsigned short f2b(float f) {     // fp32 -> bf16 RNE
  union { float f; unsigned int u; } v; v.f = f;
  unsigned int r = v.u + 0x7FFFu + ((v.u >> 16) & 1u);
  return (unsigned short)(r >> 16);
}
__device__ __forceinline__ float b2f(unsigned short b) {
  union { unsigned int u; float f; } v; v.u = ((unsigned int)b) << 16; return v.f;
}
__device__ __forceinline__ unsigned int pk2(float a, float b) {
  return (unsigned int)f2b(a) | ((unsigned int)f2b(b) << 16);
}
__device__ __forceinline__ void gl_lds16(const void* g, void* l) {
  __builtin_amdgcn_global_load_lds(
      (const __attribute__((address_space(1))) unsigned int*)g,
      (__attribute__((address_space(3))) unsigned int*)l, 16, 0, 0);
}
__device__ __forceinline__ floatx4 mfma16(short8 a, short8 b, floatx4 c) {
  return __builtin_amdgcn_mfma_f32_16x16x32_bf16(a, b, c, 0, 0, 0);
}
#define BARRIER_VM()  do { asm volatile("s_waitcnt vmcnt(0) lgkmcnt(0)" ::: "memory"); \
                           __builtin_amdgcn_s_barrier(); \
                           __builtin_amdgcn_sched_barrier(0); } while (0)

// ---------------------------------------------------------------------------
// P/Qg build GEMM, merged rows [0,MT): rows<MD diff, >=MD same.
// blockIdx.z: 0 -> P = D@W + b - xmean[c]       (W = Wdiff|Wsame)
//             1 -> Qg = D@(W G) + bg - Mg[c]    (folded Q-projection)
// A built on the fly: diff D = xmean[c]-x[gather]; same D = x[ls]-xmean[ls/16].
// ---------------------------------------------------------------------------
__global__ __launch_bounds__(256, 2) void gemm_p_qg(
    const float* __restrict__ Xg, const float* __restrict__ Xmean,
    const unsigned short* __restrict__ BtD, const unsigned short* __restrict__ BtS,
    const unsigned short* __restrict__ BtDG, const unsigned short* __restrict__ BtSG,
    const float* __restrict__ bdiff, const float* __restrict__ bsame,
    const float* __restrict__ bqg, const float* __restrict__ bsg,
    const float* __restrict__ Mg,
    unsigned short* __restrict__ P_b, unsigned short* __restrict__ Qg_b)
{
  __shared__ __align__(16) unsigned short As[2][128 * 64];
  __shared__ __align__(16) unsigned short Bs[2][64 * 64];
  const int t  = threadIdx.x;
  const int m0 = blockIdx.x * 128;
  const int n0 = blockIdx.y * 64;
  const int z  = blockIdx.z;
  const int wid = t >> 6, lane = t & 63;
  const int wm = wid >> 1, wn = wid & 1;
  const int l15 = lane & 15, lg = lane >> 4;

  const bool isDiff = (m0 < MD);
  const unsigned short* Bt = z ? (isDiff ? BtDG : BtSG) : (isDiff ? BtD : BtS);
  const float* bias = z ? (isDiff ? bqg : bsg) : (isDiff ? bdiff : bsame);
  const float* mean = z ? Mg : Xmean;
  unsigned short* OutB = z ? Qg_b : P_b;

  const int ra = t >> 1, kh = t & 1;
  const float* aptr; const float* mptr;
  float sa;
  {
    const int am = m0 + ra;
    if (isDiff) {
      const int c = am / ND, j = am - c * ND;
      const int oi = j >> 4, s = j & 15;
      const int oc = (oi < c) ? oi : oi + 1;
      aptr = Xg + (size_t)(oc * SHOT + s) * DD;
      mptr = Xmean + (size_t)c * DD;
      sa = -1.f;
    } else {
      const int ls = am - MD;
      aptr = Xg + (size_t)ls * DD;
      mptr = Xmean + (size_t)(ls >> 4) * DD;
      sa = 1.f;
    }
  }

  floatx4 acc[4][2];
  #pragma unroll
  for (int i = 0; i < 4; ++i)
    #pragma unroll
    for (int j = 0; j < 2; ++j) acc[i][j] = (floatx4){0.f, 0.f, 0.f, 0.f};

  auto stage = [&](int ks, int bufi) {
    const int k0 = ks * 64;
    #pragma unroll
    for (int it = 0; it < 2; ++it) {               // B tile 64x64
      const int L = it * 256 + t;
      const int r = L >> 3, cs = L & 7;
      const int cl = cs ^ (r & 7);
      gl_lds16(Bt + (size_t)(n0 + r) * DD + k0 + cl * 8, &Bs[bufi][0] + L * 8);
    }
    const int kb2 = k0 + kh * 32;                  // A gather+sub+cvt
    #pragma unroll
    for (int i = 0; i < 4; ++i) {
      const float4 x0  = *(const float4*)(aptr + kb2 + i * 8);
      const float4 x1  = *(const float4*)(aptr + kb2 + i * 8 + 4);
      const float4 mv0 = *(const float4*)(mptr + kb2 + i * 8);
      const float4 mv1 = *(const float4*)(mptr + kb2 + i * 8 + 4);
      i32x4 w;
      w[0] = (int)pk2(sa * (x0.x - mv0.x), sa * (x0.y - mv0.y));
      w[1] = (int)pk2(sa * (x0.z - mv0.z), sa * (x0.w - mv0.w));
      w[2] = (int)pk2(sa * (x1.x - mv1.x), sa * (x1.y - mv1.y));
      w[3] = (int)pk2(sa * (x1.z - mv1.z), sa * (x1.w - mv1.w));
      const int c  = kh * 4 + i;
      const int cw = c ^ (ra & 7);
      *(i32x4*)((char*)&As[bufi][0] + ra * 128 + cw * 16) = w;
    }
  };

  auto compute = [&](int bufi) {
    #pragma unroll
    for (int kc = 0; kc < 2; ++kc) {
      short8 af[4], bf[2];
      #pragma unroll
      for (int mt = 0; mt < 4; ++mt) {
        const int row = wm * 64 + mt * 16 + l15;
        const int cs  = (kc * 4 + lg) ^ (row & 7);
        af[mt] = *(const short8*)((const char*)&As[bufi][0] + row * 128 + cs * 16);
      }
      #pragma unroll
      for (int nt = 0; nt < 2; ++nt) {
        const int row = wn * 32 + nt * 16 + l15;
        const int cs  = (kc * 4 + lg) ^ (row & 7);
        bf[nt] = *(const short8*)((const char*)&Bs[bufi][0] + row * 128 + cs * 16);
      }
      #pragma unroll
      for (int mt = 0; mt < 4; ++mt)
        #pragma unroll
        for (int nt = 0; nt < 2; ++nt)
          acc[mt][nt] = mfma16(af[mt], bf[nt], acc[mt][nt]);
    }
  };

  stage(0, 0);
  BARRIER_VM();
  for (int ks = 0; ks < 5; ++ks) {
    if (ks + 1 < 5) stage(ks + 1, (ks + 1) & 1);
    compute(ks & 1);
    BARRIER_VM();
  }

  #pragma unroll
  for (int nt = 0; nt < 2; ++nt) {
    const int n = n0 + wn * 32 + nt * 16 + l15;
    const float bb = bias[n];
    #pragma unroll
    for (int mt = 0; mt < 4; ++mt) {
      #pragma unroll
      for (int r = 0; r < 4; ++r) {
        const int m = m0 + wm * 64 + mt * 16 + lg * 4 + r;
        const int cm = isDiff ? (m / ND) : ((m - MD) >> 4);
        const float v = acc[mt][nt][r] + bb - mean[(size_t)cm * DD + n];
        OutB[(size_t)m * DD + n] = f2b(v);
      }
    }
  }
}

// ---------------------------------------------------------------------------
// FC GEMM with virtual-F epilogue: F = O@(WvWfc) + bvf + P (never stored);
// per-row partial sums {sum F, sum F^2, sum u*F} over this block's 32-col
// wave slice -> part[m][slot][3], slot = blockIdx.y*2 + wn (10 slots = 320 c).
// ---------------------------------------------------------------------------
__global__ __launch_bounds__(256, 2) void gemm_fc(
    const unsigned short* __restrict__ A,
    const unsigned short* __restrict__ Bt,
    const float* __restrict__ bvf,
    const unsigned short* __restrict__ ResB,
    const float* __restrict__ u,
    float* __restrict__ part)
{
  __shared__ __align__(16) unsigned short As[2][128 * 64];
  __shared__ __align__(16) unsigned short Bs[2][64 * 64];
  const int t  = threadIdx.x;
  const int m0 = blockIdx.x * 128;
  const int n0 = blockIdx.y * 64;
  const int wid = t >> 6, lane = t & 63;
  const int wm = wid >> 1, wn = wid & 1;
  const int l15 = lane & 15, lg = lane >> 4;

  floatx4 acc[4][2];
  #pragma unroll
  for (int i = 0; i < 4; ++i)
    #pragma unroll
    for (int j = 0; j < 2; ++j) acc[i][j] = (floatx4){0.f, 0.f, 0.f, 0.f};

  auto stage = [&](int ks, int bufi) {
    const int k0 = ks * 64;
    #pragma unroll
    for (int it = 0; it < 2; ++it) {
      const int L = it * 256 + t;
      const int r = L >> 3, cs = L & 7;
      const int cl = cs ^ (r & 7);
      gl_lds16(Bt + (size_t)(n0 + r) * DD + k0 + cl * 8, &Bs[bufi][0] + L * 8);
    }
    #pragma unroll
    for (int it = 0; it < 4; ++it) {
      const int L = it * 256 + t;
      const int r = L >> 3, cs = L & 7;
      const int cl = cs ^ (r & 7);
      gl_lds16(A + (size_t)(m0 + r) * DD + k0 + cl * 8, &As[bufi][0] + L * 8);
    }
  };

  auto compute = [&](int bufi) {
    #pragma unroll
    for (int kc = 0; kc < 2; ++kc) {
      short8 af[4], bf[2];
      #pragma unroll
      for (int mt = 0; mt < 4; ++mt) {
        const int row = wm * 64 + mt * 16 + l15;
        const int cs  = (kc * 4 + lg) ^ (row & 7);
        af[mt] = *(const short8*)((const char*)&As[bufi][0] + row * 128 + cs * 16);
      }
      #pragma unroll
      for (int nt = 0; nt < 2; ++nt) {
        const int row = wn * 32 + nt * 16 + l15;
        const int cs  = (kc * 4 + lg) ^ (row & 7);
        bf[nt] = *(const short8*)((const char*)&Bs[bufi][0] + row * 128 + cs * 16);
      }
      #pragma unroll
      for (int mt = 0; mt < 4; ++mt)
        #pragma unroll
        for (int nt = 0; nt < 2; ++nt)
          acc[mt][nt] = mfma16(af[mt], bf[nt], acc[mt][nt]);
    }
  };

  stage(0, 0);
  BARRIER_VM();
  for (int ks = 0; ks < 5; ++ks) {
    if (ks + 1 < 5) stage(ks + 1, (ks + 1) & 1);
    compute(ks & 1);
    BARRIER_VM();
  }

  const int slot = blockIdx.y * 2 + wn;
  #pragma unroll
  for (int mt = 0; mt < 4; ++mt) {
    float ps0[4] = {0.f,0.f,0.f,0.f}, ps1[4] = {0.f,0.f,0.f,0.f}, ps2[4] = {0.f,0.f,0.f,0.f};
    #pragma unroll
    for (int nt = 0; nt < 2; ++nt) {
      const int n = n0 + wn * 32 + nt * 16 + l15;
      const float bb = bvf[n];
      const float un = u[n];
      #pragma unroll
      for (int r = 0; r < 4; ++r) {
        const int m = m0 + wm * 64 + mt * 16 + lg * 4 + r;
        const float v = acc[mt][nt][r] + bb + b2f(ResB[(size_t)m * DD + n]);
        ps0[r] += v; ps1[r] += v * v; ps2[r] += un * v;
      }
    }
    #pragma unroll
    for (int r = 0; r < 4; ++r) {
      #pragma unroll
      for (int mk = 1; mk < 16; mk <<= 1) {
        ps0[r] += __shfl_xor(ps0[r], mk);
        ps1[r] += __shfl_xor(ps1[r], mk);
        ps2[r] += __shfl_xor(ps2[r], mk);
      }
      if (l15 == 0) {
        const int m = m0 + wm * 64 + mt * 16 + lg * 4 + r;
        float* pp = part + ((size_t)m * 10 + slot) * 3;
        pp[0] = ps0[r]; pp[1] = ps1[r]; pp[2] = ps2[r];
      }
    }
  }
}

// ---------------------------------------------------------------------------
// 16x16 MFMA flash attention, merged: blocks [0,1024) diff, [1024,1088) same.
// Round-7-proven body + T13 defer-max (THR=8).
// ---------------------------------------------------------------------------
__global__ __launch_bounds__(256, 2) void attn16(
    const unsigned short* __restrict__ Qall, const unsigned short* __restrict__ Pall,
    const unsigned short* __restrict__ PtD, const unsigned short* __restrict__ PtS,
    unsigned short* __restrict__ Oall)
{
  __shared__ __align__(16) char smem[64 * 656];   // 41984B
  const int t = threadIdx.x;
  const int wid = t >> 6, lane = t & 63;
  const int l15 = lane & 15, lg = lane >> 4;

  int bx = blockIdx.x;
  const int nwg = gridDim.x;                      // 1088, %8==0
  bx = (bx & 7) * (nwg >> 3) + (bx >> 3);         // XCD swizzle

  const unsigned short *Qg, *Pk, *Pt; unsigned short* Ob;
  int cls, blkq, qRows, kPitch, vtPitch, nKT, validKV, qTiles;
  if (bx < 1024) {
    cls = bx >> 4; blkq = bx & 15;
    Qg = Qall; Pk = Pall; Pt = PtD; Ob = Oall;
    qRows = ND; kPitch = ND; vtPitch = 1024; nKT = 32; validKV = ND; qTiles = 63;
  } else {
    cls = bx - 1024; blkq = 0;
    Qg = Qall + (size_t)MD * DD; Pk = Pall + (size_t)MD * DD;
    Pt = PtS; Ob = Oall + (size_t)MD * DD;
    qRows = 16; kPitch = 16; vtPitch = 32; nKT = 1; validKV = 16; qTiles = 1;
  }
  const int qt0 = blkq * 4 + wid;
  const bool wValid = qt0 < qTiles;
  const int qt = wValid ? qt0 : qTiles - 1;

  // Q fragments (B operand): lane holds Q[q=l15][kd = kc*32 + lg*8 + j]
  short8 qf[10];
  {
    const unsigned short* qrow = Qg + ((size_t)cls * qRows + qt * 16 + l15) * DD;
    #pragma unroll
    for (int kc = 0; kc < 10; ++kc) qf[kc] = *(const short8*)(qrow + kc * 32 + lg * 8);
  }

  floatx4 o[20];
  #pragma unroll
  for (int i = 0; i < 20; ++i) o[i] = (floatx4){0.f, 0.f, 0.f, 0.f};
  float mrun = -1e30f, lsum = 0.f;
  const float scale = 0.05590169943749474f;       // 1/sqrt(320)

  for (int kt = 0; kt < nKT; ++kt) {
    __syncthreads();
    #pragma unroll
    for (int it = 0; it < 5; ++it) {              // K = P rows [32 kv][320 d]
      const int L = it * 256 + t;
      const int r = L / 40, c = L - (L / 40) * 40;
      const int cl = (c & ~7) | ((c & 7) ^ (r & 7));
      gl_lds16(Pk + ((size_t)cls * kPitch + kt * 32 + r) * DD + cl * 8, smem + L * 16);
    }
    #pragma unroll
    for (int it = 0; it < 5; ++it) {              // V = P^T [320 d][32 kv]
      const int L = it * 256 + t;
      const int d = L >> 2, c = L & 3;
      const int cl = c ^ ((d >> 1) & 3);
      gl_lds16(Pt + ((size_t)cls * DD + d) * vtPitch + kt * 32 + cl * 8,
               smem + 20480 + L * 16);
    }
    __syncthreads();

    floatx4 st0 = (floatx4){0.f,0.f,0.f,0.f}, st1 = (floatx4){0.f,0.f,0.f,0.f};
    __builtin_amdgcn_s_setprio(1);
    #pragma unroll
    for (int kc = 0; kc < 10; ++kc) {
      const int c = kc * 4 + lg;
      const int cl = (c & ~7) | ((c & 7) ^ (l15 & 7));
      const short8 k0f = *(const short8*)(smem + l15 * 640 + cl * 16);
      const short8 k1f = *(const short8*)(smem + (16 + l15) * 640 + cl * 16);
      st0 = mfma16(k0f, qf[kc], st0);
      st1 = mfma16(k1f, qf[kc], st1);
    }
    __builtin_amdgcn_s_setprio(0);

    float s[8];
    #pragma unroll
    for (int r = 0; r < 4; ++r) { s[r] = st0[r] * scale; s[4 + r] = st1[r] * scale; }
    const int kvb = kt * 32 + lg * 4;
    #pragma unroll
    for (int r = 0; r < 4; ++r) {
      if (kvb + r      >= validKV) s[r]     = -1e30f;
      if (kvb + 16 + r >= validKV) s[4 + r] = -1e30f;
    }
    float mt_ = s[0];
    #pragma unroll
    for (int i = 1; i < 8; ++i) mt_ = fmaxf(mt_, s[i]);
    mt_ = fmaxf(mt_, __shfl_xor(mt_, 16));
    mt_ = fmaxf(mt_, __shfl_xor(mt_, 32));
    if (!__all(mt_ - mrun <= 8.0f)) {             // T13 defer-max
      const float newm = fmaxf(mrun, mt_);
      const float alpha = __expf(mrun - newm);
      lsum *= alpha;
      #pragma unroll
      for (int i = 0; i < 20; ++i) {
        o[i][0] *= alpha; o[i][1] *= alpha; o[i][2] *= alpha; o[i][3] *= alpha;
      }
      mrun = newm;
    }
    float p[8]; float rs = 0.f;
    #pragma unroll
    for (int i = 0; i < 8; ++i) { p[i] = __expf(s[i] - mrun); rs += p[i]; }
    rs += __shfl_xor(rs, 16);
    rs += __shfl_xor(rs, 32);
    lsum += rs;

    const unsigned int pk00 = pk2(p[0], p[1]), pk01 = pk2(p[2], p[3]);
    const unsigned int pk10 = pk2(p[4], p[5]), pk11 = pk2(p[6], p[7]);
    const int src0 = l15 + ((lane >> 4) & 1) * 32;
    const int src1 = src0 + 16;
    const int y0 = __shfl((int)pk00, src0), y1 = __shfl((int)pk01, src0);
    const int y2 = __shfl((int)pk00, src1), y3 = __shfl((int)pk01, src1);
    const int z0 = __shfl((int)pk10, src0), z1 = __shfl((int)pk11, src0);
    const int z2 = __shfl((int)pk10, src1), z3 = __shfl((int)pk11, src1);
    const bool hi = lane >= 32;
    union { i32x4 w; short8 v; } pf;
    pf.w[0] = hi ? z0 : y0; pf.w[1] = hi ? z1 : y1;
    pf.w[2] = hi ? z2 : y2; pf.w[3] = hi ? z3 : y3;

    const int vswz = (l15 >> 1) & 3;
    __builtin_amdgcn_s_setprio(1);
    #pragma unroll
    for (int dt = 0; dt < 20; ++dt) {
      const int d = dt * 16 + l15;
      const short8 a = *(const short8*)(smem + 20480 + d * 64 + ((lg ^ vswz) << 4));
      o[dt] = mfma16(a, pf.v, o[dt]);
    }
    __builtin_amdgcn_s_setprio(0);
  }

  const float invl = 1.f / lsum;
  __syncthreads();
  char* ep = smem + wid * 10496;
  #pragma unroll
  for (int dt = 0; dt < 20; ++dt) {
    const unsigned int w0 = pk2(o[dt][0] * invl, o[dt][1] * invl);
    const unsigned int w1 = pk2(o[dt][2] * invl, o[dt][3] * invl);
    *(unsigned int*)(ep + l15 * 656 + (dt * 16 + lg * 4) * 2)     = w0;
    *(unsigned int*)(ep + l15 * 656 + (dt * 16 + lg * 4 + 2) * 2) = w1;
  }
  __syncthreads();
  if (wValid) {
    #pragma unroll
    for (int it = 0; it < 10; ++it) {
      const int flat = it * 64 + lane;
      const int q = flat / 40, c = flat - (flat / 40) * 40;
      const i32x4 v = *(const i32x4*)(ep + q * 656 + c * 16);
      *(i32x4*)(Ob + ((size_t)cls * qRows + qt * 16 + q) * DD + c * 8) = v;
    }
  }
}

// ---------------------------------------------------------------------------
// Merged transpose: blocks [0,1024) diff P -> PtD; [1024,1088) same P -> PtS.
// ---------------------------------------------------------------------------
__global__ __launch_bounds__(256) void transpose_pm(
    const unsigned short* __restrict__ Pall,
    unsigned short* __restrict__ PtD, unsigned short* __restrict__ PtS)
{
  __shared__ __align__(16) unsigned short Ls[64 * 72];
  const int t = threadIdx.x;
  const int bx = blockIdx.x;
  const unsigned short* P; unsigned short* PtG;
  int cls, kvt, rowsP, vtPitch;
  if (bx < 1024) { cls = bx >> 4; kvt = bx & 15; P = Pall; PtG = PtD;
                   rowsP = ND; vtPitch = 1024; }
  else { cls = bx - 1024; kvt = 0; P = Pall + (size_t)MD * DD; PtG = PtS;
         rowsP = 16; vtPitch = 32; }
  const int dt = blockIdx.y;
  #pragma unroll
  for (int i = 0; i < 2; ++i) {
    const int flat = t + i * 256;
    const int r = flat >> 3, c = flat & 7;
    const int kv = kvt * 64 + r;
    i32x4 v = {0, 0, 0, 0};
    if (kv < rowsP)
      v = *(const i32x4*)(P + ((size_t)cls * rowsP + kv) * DD + dt * 64 + c * 8);
    *(i32x4*)(&Ls[r * 72 + c * 8]) = v;
  }
  __syncthreads();
  #pragma unroll
  for (int i = 0; i < 2; ++i) {
    const int flat = t + i * 256;
    const int r2 = flat >> 3, c2 = flat & 7;
    if (kvt * 64 + c2 * 8 < vtPitch) {
      union { unsigned short e[8]; i32x4 v; } u;
      #pragma unroll
      for (int jj = 0; jj < 8; ++jj) u.e[jj] = Ls[(c2 * 8 + jj) * 72 + r2];
      *(i32x4*)(PtG + ((size_t)cls * DD + dt * 64 + r2) * vtPitch + kvt * 64 + c2 * 8) = u.v;
    }
  }
}

// ---------------------------------------------------------------------------
// Weight prep 1 (grid.z): z0 BtD=(Wdiff)^T bf16; z1 BtS=(Wsame)^T bf16;
// z2 GfT[n][k] = sum_m Wk[n,m] Wq[k,m] (fp32); z3 BtVF[n][k]=sum_m Wfc[m,n]Wv[k,m].
// ---------------------------------------------------------------------------
__global__ __launch_bounds__(256) void wprep(
    const float* __restrict__ Wsame, const float* __restrict__ Wdiff,
    const float* __restrict__ Wk, const float* __restrict__ Wq,
    const float* __restrict__ Wfc, const float* __restrict__ Wv,
    unsigned short* __restrict__ BtS, unsigned short* __restrict__ BtD,
    float* __restrict__ GfT, unsigned short* __restrict__ BtVF)
{
  __shared__ float Ls[64 * 68];
  const int t = threadIdx.x;
  const int z = blockIdx.z;
  if (z < 2) {
    const float* W = z ? Wdiff : Wsame;
    unsigned short* Wt = z ? BtD : BtS;
    const int k0 = blockIdx.x * 64, n0 = blockIdx.y * 64;
    #pragma unroll
    for (int i = 0; i < 4; ++i) {
      const int flat = t + i * 256;
      const int r = flat >> 4, c = (flat & 15) * 4;
      *(float4*)&Ls[r * 68 + c] = *(const float4*)(W + (size_t)(k0 + r) * DD + n0 + c);
    }
    __syncthreads();
    #pragma unroll
    for (int j = 0; j < 2; ++j) {
      const int flat = t + j * 256;
      const int r2 = flat >> 3, c2 = flat & 7;
      union { unsigned short e[8]; i32x4 v; } u;
      #pragma unroll
      for (int jj = 0; jj < 8; ++jj) u.e[jj] = f2b(Ls[(c2 * 8 + jj) * 68 + r2]);
      *(i32x4*)(Wt + (size_t)(n0 + r2) * DD + k0 + c2 * 8) = u.v;
    }
  } else {
    const int trL = (z == 3);
    const float* L = trL ? Wfc : Wk;
    const float* R = trL ? Wv : Wq;
    float* Lsm = Ls;
    float* Rsm = Ls + 16 * 68;
    const int n0 = blockIdx.x * 64, k0 = blockIdx.y * 64;
    const int tn4 = (t & 15) * 4, tk4 = (t >> 4) * 4;
    float acc[4][4] = {};
    for (int ms = 0; ms < DD; ms += 16) {
      const int lr = t >> 4, lc = (t & 15);
      #pragma unroll
      for (int i = 0; i < 4; ++i) {
        const int nn = lc * 4 + i;
        Lsm[lr * 68 + nn] = trL ? L[(size_t)(ms + lr) * DD + n0 + nn]
                                : L[(size_t)(n0 + nn) * DD + ms + lr];
        Rsm[lr * 68 + nn] = R[(size_t)(k0 + nn) * DD + ms + lr];
      }
      __syncthreads();
      #pragma unroll
      for (int mm = 0; mm < 16; ++mm) {
        float la[4], rb[4];
        #pragma unroll
        for (int i = 0; i < 4; ++i) { la[i] = Lsm[mm * 68 + tn4 + i]; rb[i] = Rsm[mm * 68 + tk4 + i]; }
        #pragma unroll
        for (int i = 0; i < 4; ++i)
          #pragma unroll
          for (int j = 0; j < 4; ++j) acc[i][j] += la[i] * rb[j];
      }
      __syncthreads();
    }
    if (z == 2) {
      #pragma unroll
      for (int i = 0; i < 4; ++i)
        #pragma unroll
        for (int j = 0; j < 4; ++j)
          GfT[(size_t)(n0 + tn4 + i) * DD + k0 + tk4 + j] = acc[i][j];
    } else {
      #pragma unroll
      for (int i = 0; i < 4; ++i)
        #pragma unroll
        for (int j = 0; j < 4; ++j)
          BtVF[(size_t)(n0 + tn4 + i) * DD + k0 + tk4 + j] = f2b(acc[i][j]);
    }
  }
}

// ---------------------------------------------------------------------------
// Weight prep 2 (needs GfT, vbias): z0 BtDG[n][k]=sum_j Wdiff[k][j] GfT[n][j];
// z1 BtSG (Wsame); z2: x==0 Mg[c][n]=xmean[c].GfT[n], x==1 bqg, x==2 bsg.
// ---------------------------------------------------------------------------
__global__ __launch_bounds__(256) void wprep2(
    const float* __restrict__ GfT,
    const float* __restrict__ Wdiff, const float* __restrict__ Wsame,
    const float* __restrict__ Xmean,
    const float* __restrict__ bdiff, const float* __restrict__ bsame,
    const float* __restrict__ vbias,
    unsigned short* __restrict__ BtDG, unsigned short* __restrict__ BtSG,
    float* __restrict__ Mg, float* __restrict__ bqg, float* __restrict__ bsg)
{
  __shared__ float Ls[2 * 16 * 68];
  const int t = threadIdx.x;
  const int z = blockIdx.z;
  if (z < 2) {
    const float* R = z ? Wsame : Wdiff;
    unsigned short* Bt = z ? BtSG : BtDG;
    float* Lsm = Ls;
    float* Rsm = Ls + 16 * 68;
    const int n0 = blockIdx.x * 64, k0 = blockIdx.y * 64;
    const int tn4 = (t & 15) * 4, tk4 = (t >> 4) * 4;
    float acc[4][4] = {};
    for (int ms = 0; ms < DD; ms += 16) {
      const int lr = t >> 4, lc = (t & 15);
      #pragma unroll
      for (int i = 0; i < 4; ++i) {
        const int nn = lc * 4 + i;
        Lsm[lr * 68 + nn] = GfT[(size_t)(n0 + nn) * DD + ms + lr];
        Rsm[lr * 68 + nn] = R[(size_t)(k0 + nn) * DD + ms + lr];
      }
      __syncthreads();
      #pragma unroll
      for (int mm = 0; mm < 16; ++mm) {
        float la[4], rb[4];
        #pragma unroll
        for (int i = 0; i < 4; ++i) { la[i] = Lsm[mm * 68 + tn4 + i]; rb[i] = Rsm[mm * 68 + tk4 + i]; }
        #pragma unroll
        for (int i = 0; i < 4; ++i)
          #pragma unroll
          for (int j = 0; j < 4; ++j) acc[i][j] += la[i] * rb[j];
      }
      __syncthreads();
    }
    #pragma unroll
    for (int i = 0; i < 4; ++i)
      #pragma unroll
      for (int j = 0; j < 4; ++j)
        Bt[(size_t)(n0 + tn4 + i) * DD + k0 + tk4 + j] = f2b(acc[i][j]);
  } else {
    const int n0 = blockIdx.y * 64;
    if (blockIdx.x == 0) {                        // Mg chunk
      for (int idx = t; idx < 64 * 64; idx += 256) {
        const int c = idx >> 6, nn = n0 + (idx & 63);
        float a = 0.f;
        for (int k = 0; k < DD; ++k) a += Xmean[c * DD + k] * GfT[(size_t)nn * DD + k];
        Mg[c * DD + nn] = a;
      }
    } else if (blockIdx.x == 1) {                 // bqg
      if (t < 64) {
        const int nn = n0 + t;
        float a = 0.f;
        for (int k = 0; k < DD; ++k) a += bdiff[k] * GfT[(size_t)nn * DD + k];
        bqg[nn] = a + vbias[nn];
      }
    } else if (blockIdx.x == 2) {                 // bsg
      if (t < 64) {
        const int nn = n0 + t;
        float a = 0.f;
        for (int k = 0; k < DD; ++k) a += bsame[k] * GfT[(size_t)nn * DD + k];
        bsg[nn] = a + vbias[nn];
      }
    }
  }
}

// vbias[n]=sum Wk[n,m]bq[m]; bvf[n]=sum Wfc[m,n]bv[m]+bfc[n]; u=lng*Wout;
// scal = {sum lng*Wout, sum lnb*Wout + bout}
__global__ __launch_bounds__(960) void wbias(
    const float* __restrict__ Wk, const float* __restrict__ bq,
    const float* __restrict__ Wfc, const float* __restrict__ bv,
    const float* __restrict__ bfc,
    const float* __restrict__ lng, const float* __restrict__ lnb,
    const float* __restrict__ Wout, const float* __restrict__ bout,
    float* __restrict__ v, float* __restrict__ bvf,
    float* __restrict__ u, float* __restrict__ scal)
{
  const int t = threadIdx.x;
  if (t < DD) {
    float a = 0.f;
    for (int m = 0; m < DD; ++m) a += Wk[(size_t)t * DD + m] * bq[m];
    v[t] = a;
  } else if (t < 2 * DD) {
    const int n = t - DD;
    float a = 0.f;
    for (int m = 0; m < DD; ++m) a += Wfc[(size_t)m * DD + n] * bv[m];
    bvf[n] = a + bfc[n];
  } else if (t < 3 * DD) {
    const int n = t - 2 * DD;
    u[n] = lng[n] * Wout[n];
    if (n == 0) {
      float su = 0.f, b0 = 0.f;
      for (int k = 0; k < DD; ++k) { su += lng[k] * Wout[k]; b0 += lnb[k] * Wout[k]; }
      scal[0] = su; scal[1] = b0 + bout[0];
    }
  }
}

// logits from virtual-F partials: logit = inv*(sUF - mu*sU) + B0
__global__ __launch_bounds__(256) void logits_k(
    const float* __restrict__ part, const float* __restrict__ scal,
    float* __restrict__ logits)
{
  const int m = blockIdx.x * 256 + threadIdx.x;
  const float* pp = part + (size_t)m * 30;
  float sF = 0.f, sF2 = 0.f, sUF = 0.f;
  #pragma unroll
  for (int s = 0; s < 10; ++s) { sF += pp[s * 3]; sF2 += pp[s * 3 + 1]; sUF += pp[s * 3 + 2]; }
  const float mu  = sF * (1.f / DD);
  const float var = sF2 * (1.f / DD) - mu * mu;
  const float inv = rsqrtf(var + LN_EPS);
  logits[m] = inv * (sUF - mu * scal[0]) + scal[1];
}

// ---------------------------------------------------------------------------
// Final: per-class softmax over logits, weighted mean of P (bf16).
// ---------------------------------------------------------------------------
__global__ __launch_bounds__(320) void final_reduce(
    const float* __restrict__ logits_s, const float* __restrict__ logits_d,
    const unsigned short* __restrict__ Ps, const unsigned short* __restrict__ Pd,
    float* __restrict__ out)
{
  const int c = blockIdx.x;
  const int t = threadIdx.x;
  __shared__ float w[16 + ND];
  __shared__ float red[5];
  if (t < 16) w[t] = logits_s[c * 16 + t];
  for (int j = t; j < ND; j += 320) w[16 + j] = logits_d[c * ND + j];
  __syncthreads();
  if (t == 0) {
    float mx = w[0];
    #pragma unroll
    for (int i = 1; i < 16; ++i) mx = fmaxf(mx, w[i]);
    float ssum = 0.f;
    #pragma unroll
    for (int i = 0; i < 16; ++i) { const float e = __expf(w[i] - mx); w[i] = e; ssum += e; }
    const float inv = 1.f / ssum;
    #pragma unroll
    for (int i = 0; i < 16; ++i) w[i] *= inv;
  }
  float lm = -1e30f;
  for (int j = t; j < ND; j += 320) lm = fmaxf(lm, w[16 + j]);
  #pragma unroll
  for (int off = 32; off; off >>= 1) lm = fmaxf(lm, __shfl_xor(lm, off));
  if ((t & 63) == 0) red[t >> 6] = lm;
  __syncthreads();
  const float mx = fmaxf(fmaxf(fmaxf(red[0], red[1]), fmaxf(red[2], red[3])), red[4]);
  float ls = 0.f;
  for (int j = t; j < ND; j += 320) { const float e = __expf(w[16 + j] - mx); w[16 + j] = e; ls += e; }
  #pragma unroll
  for (int off = 32; off; off >>= 1) ls += __shfl_xor(ls, off);
  __syncthreads();
  if ((t & 63) == 0) red[t >> 6] = ls;
  __syncthreads();
  const float inv = 1.f / (red[0] + red[1] + red[2] + red[3] + red[4]);
  for (int j = t; j < ND; j += 320) w[16 + j] *= inv;
  __syncthreads();
  float acc = 0.f;
  const unsigned short* Psc = Ps + (size_t)c * SHOT * DD + t;
  const unsigned short* Pdc = Pd + (size_t)c * ND * DD + t;
  #pragma unroll 4
  for (int i = 0; i < 16; ++i) acc += w[i] * b2f(Psc[(size_t)i * DD]);
  for (int j = 0; j < ND; ++j) acc += w[16 + j] * b2f(Pdc[(size_t)j * DD]);
  out[c * DD + t] = acc * (1.f / 1024.f);
}

// ---------------------------------------------------------------------------
extern "C" void kernel_launch(void* const* d_in, const int* in_sizes, int n_in,
                              void* d_out, int out_size, void* d_ws, size_t ws_size,
                              hipStream_t stream)
{
  const float* xmean = (const float*)d_in[0];
  const float* x     = (const float*)d_in[1];
  const float* Wsame = (const float*)d_in[2];
  const float* bsame = (const float*)d_in[3];
  const float* Wdiff = (const float*)d_in[4];
  const float* bdiff = (const float*)d_in[5];
  const float* Wq    = (const float*)d_in[6];
  const float* bq    = (const float*)d_in[7];
  const float* Wk    = (const float*)d_in[8];
  const float* bk    = (const float*)d_in[9];   (void)bk; // row-const in softmax
  const float* Wv    = (const float*)d_in[10];
  const float* bv    = (const float*)d_in[11];
  const float* Wfc   = (const float*)d_in[12];
  const float* bfc   = (const float*)d_in[13];
  const float* lng   = (const float*)d_in[14];
  const float* lnb   = (const float*)d_in[15];
  const float* Wout  = (const float*)d_in[16];
  const float* boutp = (const float*)d_in[17];
  float* outp = (float*)d_out;

  char* base = (char*)d_ws;
  size_t off = 0;
  auto alloc = [&](size_t bytes) { char* p = base + off; off += (bytes + 255) & ~(size_t)255; return p; };

  const size_t WB = (size_t)DD * DD * 2;
  unsigned short* BtS  = (unsigned short*)alloc(WB);
  unsigned short* BtD  = (unsigned short*)alloc(WB);
  unsigned short* BtDG = (unsigned short*)alloc(WB);
  unsigned short* BtSG = (unsigned short*)alloc(WB);
  unsigned short* BtVF = (unsigned short*)alloc(WB);
  float* GfT   = (float*)alloc((size_t)DD * DD * 4);
  float* Mg    = (float*)alloc((size_t)CC * DD * 4);
  float* vbias = (float*)alloc(DD * 4);
  float* bvf   = (float*)alloc(DD * 4);
  float* bqg   = (float*)alloc(DD * 4);
  float* bsg   = (float*)alloc(DD * 4);
  float* ubuf  = (float*)alloc(DD * 4);
  float* scal  = (float*)alloc(2 * 4);
  unsigned short* P_b  = (unsigned short*)alloc((size_t)MT * DD * 2);
  unsigned short* Qg_b = (unsigned short*)alloc((size_t)MT * DD * 2);
  unsigned short* O_b  = (unsigned short*)alloc((size_t)MT * DD * 2);
  unsigned short* PtD  = (unsigned short*)alloc((size_t)CC * DD * 1024 * 2);
  unsigned short* PtS  = (unsigned short*)alloc((size_t)CC * DD * 32 * 2);
  float* part   = (float*)alloc((size_t)MT * 30 * 4);
  float* logits = (float*)alloc((size_t)MT * 4);

  const dim3 blk(256);
  // ---- weight prep ----
  wprep<<<dim3(5, 5, 4), blk, 0, stream>>>(Wsame, Wdiff, Wk, Wq, Wfc, Wv,
                                           BtS, BtD, GfT, BtVF);
  wbias<<<dim3(1), dim3(960), 0, stream>>>(Wk, bq, Wfc, bv, bfc, lng, lnb, Wout, boutp,
                                           vbias, bvf, ubuf, scal);
  wprep2<<<dim3(5, 5, 3), blk, 0, stream>>>(GfT, Wdiff, Wsame, xmean, bdiff, bsame,
                                            vbias, BtDG, BtSG, Mg, bqg, bsg);
  // ---- P and Qg, both branches, one dispatch (z: 0=P, 1=Qg) ----
  gemm_p_qg<<<dim3(MT / 128, 5, 2), blk, 0, stream>>>(
      x, xmean, BtD, BtS, BtDG, BtSG, bdiff, bsame, bqg, bsg, Mg, P_b, Qg_b);
  // ---- P^T (merged diff+same) ----
  transpose_pm<<<dim3(1088, 5), blk, 0, stream>>>(P_b, PtD, PtS);
  // ---- attention (merged diff+same) ----
  attn16<<<dim3(1088), blk, 0, stream>>>(Qg_b, P_b, PtD, PtS, O_b);
  // ---- FC with virtual-F partials epilogue ----
  gemm_fc<<<dim3(MT / 128, 5), blk, 0, stream>>>(O_b, BtVF, bvf, P_b, ubuf, part);
  // ---- logits from partials ----
  logits_k<<<dim3(MT / 256), blk, 0, stream>>>(part, scal, logits);
  // ---- final softmax-weighted mean ----
  final_reduce<<<dim3(CC), dim3(320), 0, stream>>>(logits + MD, logits,
                                                   P_b + (size_t)MD * DD, P_b, outp);
}

// Round 11
// 491.985 us; speedup vs baseline: 1.4220x; 1.4220x over previous
//
#include <hip/hip_runtime.h>

#define CC   64
#define SHOT 16
#define DD   320
#define ND   1008            // (CC-1)*SHOT
#define MS   (CC * SHOT)     // 1024
#define MD   (CC * ND)       // 64512
#define MT   (MD + MS)       // 65536 = 512*128
#define LN_EPS 1e-5f

typedef __attribute__((ext_vector_type(8)))  short short8;    // 8 bf16 = 4 VGPR
typedef __attribute__((ext_vector_type(4)))  float floatx4;
typedef __attribute__((ext_vector_type(4)))  int i32x4;

__device__ __forceinline__ unsigned short f2b(float f) {     // fp32 -> bf16 RNE
  union { float f; unsigned int u; } v; v.f = f;
  unsigned int r = v.u + 0x7FFFu + ((v.u >> 16) & 1u);
  return (unsigned short)(r >> 16);
}
__device__ __forceinline__ float b2f(unsigned short b) {
  union { unsigned int u; float f; } v; v.u = ((unsigned int)b) << 16; return v.f;
}
__device__ __forceinline__ unsigned int pk2(float a, float b) {
  return (unsigned int)f2b(a) | ((unsigned int)f2b(b) << 16);
}
__device__ __forceinline__ void gl_lds16(const void* g, void* l) {
  __builtin_amdgcn_global_load_lds(
      (const __attribute__((address_space(1))) unsigned int*)g,
      (__attribute__((address_space(3))) unsigned int*)l, 16, 0, 0);
}
__device__ __forceinline__ floatx4 mfma16(short8 a, short8 b, floatx4 c) {
  return __builtin_amdgcn_mfma_f32_16x16x32_bf16(a, b, c, 0, 0, 0);
}
#define BARRIER_VM()  do { asm volatile("s_waitcnt vmcnt(0) lgkmcnt(0)" ::: "memory"); \
                           __builtin_amdgcn_s_barrier(); \
                           __builtin_amdgcn_sched_barrier(0); } while (0)

// ---------------------------------------------------------------------------
// MFMA GEMM over the MERGED row space [0,65536): rows <MD are diff-branch,
// rows >=MD are same-branch. BM=128 BN=64 BK=64, 4 waves (2x2).
// mode 0: A bf16 passthrough, weights BtDiff/biasDiff for ALL rows,
//         optional residual ResB, no mean-sub.
// mode 3: P-build. diff: A=xmean[c]-x[gather], W=BtDiff,b=biasDiff;
//         same: A=x[ls]-xmean[ls/16], W=BtSame,b=biasSame. Epilogue subtracts
//         xmean[class][n] for both regions.
// ---------------------------------------------------------------------------
__global__ __launch_bounds__(256, 2) void gemm_mfma(
    const unsigned short* __restrict__ A,
    const float* __restrict__ Xg, const float* __restrict__ Xmean,
    const int mode,
    const unsigned short* __restrict__ BtDiff,
    const unsigned short* __restrict__ BtSame,
    const float* __restrict__ biasDiff, const float* __restrict__ biasSame,
    unsigned short* __restrict__ OutB,
    const unsigned short* __restrict__ ResB)
{
  __shared__ __align__(16) unsigned short As[2][128 * 64];
  __shared__ __align__(16) unsigned short Bs[2][64 * 64];
  const int t  = threadIdx.x;
  const int m0 = blockIdx.x * 128;
  const int n0 = blockIdx.y * 64;
  const int wid = t >> 6, lane = t & 63;
  const int wm = wid >> 1, wn = wid & 1;
  const int l15 = lane & 15, lg = lane >> 4;

  const bool isDiff = (m0 < MD);
  const unsigned short* Bt = (mode == 3 && !isDiff) ? BtSame : BtDiff;
  const float* bias = (mode == 3 && !isDiff) ? biasSame : biasDiff;

  const int ra = t >> 1, kh = t & 1;
  const float* aptr = nullptr; const float* mptr = nullptr;
  float sa = 1.f;
  if (mode == 3) {
    const int am = m0 + ra;
    if (isDiff) {
      const int c = am / ND, j = am - c * ND;
      const int oi = j >> 4, s = j & 15;
      const int oc = (oi < c) ? oi : oi + 1;
      aptr = Xg + (size_t)(oc * SHOT + s) * DD;
      mptr = Xmean + (size_t)c * DD;
      sa = -1.f;
    } else {
      const int ls = am - MD;
      aptr = Xg + (size_t)ls * DD;
      mptr = Xmean + (size_t)(ls >> 4) * DD;
      sa = 1.f;
    }
  }

  floatx4 acc[4][2];
  #pragma unroll
  for (int i = 0; i < 4; ++i)
    #pragma unroll
    for (int j = 0; j < 2; ++j) acc[i][j] = (floatx4){0.f, 0.f, 0.f, 0.f};

  auto stage = [&](int ks, int bufi) {
    const int k0 = ks * 64;
    #pragma unroll
    for (int it = 0; it < 2; ++it) {               // B tile 64x64
      const int L = it * 256 + t;
      const int r = L >> 3, cs = L & 7;
      const int cl = cs ^ (r & 7);
      gl_lds16(Bt + (size_t)(n0 + r) * DD + k0 + cl * 8, &Bs[bufi][0] + L * 8);
    }
    if (mode == 0) {
      #pragma unroll
      for (int it = 0; it < 4; ++it) {             // A tile 128x64
        const int L = it * 256 + t;
        const int r = L >> 3, cs = L & 7;
        const int cl = cs ^ (r & 7);
        gl_lds16(A + (size_t)(m0 + r) * DD + k0 + cl * 8, &As[bufi][0] + L * 8);
      }
    } else {                                        // fp32 gather+sub+cvt
      const int kb2 = k0 + kh * 32;
      #pragma unroll
      for (int i = 0; i < 4; ++i) {
        const float4 x0  = *(const float4*)(aptr + kb2 + i * 8);
        const float4 x1  = *(const float4*)(aptr + kb2 + i * 8 + 4);
        const float4 mv0 = *(const float4*)(mptr + kb2 + i * 8);
        const float4 mv1 = *(const float4*)(mptr + kb2 + i * 8 + 4);
        i32x4 w;
        w[0] = (int)pk2(sa * (x0.x - mv0.x), sa * (x0.y - mv0.y));
        w[1] = (int)pk2(sa * (x0.z - mv0.z), sa * (x0.w - mv0.w));
        w[2] = (int)pk2(sa * (x1.x - mv1.x), sa * (x1.y - mv1.y));
        w[3] = (int)pk2(sa * (x1.z - mv1.z), sa * (x1.w - mv1.w));
        const int c  = kh * 4 + i;
        const int cw = c ^ (ra & 7);
        *(i32x4*)((char*)&As[bufi][0] + ra * 128 + cw * 16) = w;
      }
    }
  };

  auto compute = [&](int bufi) {
    #pragma unroll
    for (int kc = 0; kc < 2; ++kc) {
      short8 af[4], bf[2];
      #pragma unroll
      for (int mt = 0; mt < 4; ++mt) {
        const int row = wm * 64 + mt * 16 + l15;
        const int cs  = (kc * 4 + lg) ^ (row & 7);
        af[mt] = *(const short8*)((const char*)&As[bufi][0] + row * 128 + cs * 16);
      }
      #pragma unroll
      for (int nt = 0; nt < 2; ++nt) {
        const int row = wn * 32 + nt * 16 + l15;
        const int cs  = (kc * 4 + lg) ^ (row & 7);
        bf[nt] = *(const short8*)((const char*)&Bs[bufi][0] + row * 128 + cs * 16);
      }
      #pragma unroll
      for (int mt = 0; mt < 4; ++mt)
        #pragma unroll
        for (int nt = 0; nt < 2; ++nt)
          acc[mt][nt] = mfma16(af[mt], bf[nt], acc[mt][nt]);
    }
  };

  stage(0, 0);
  BARRIER_VM();
  for (int ks = 0; ks < 5; ++ks) {
    if (ks + 1 < 5) stage(ks + 1, (ks + 1) & 1);
    compute(ks & 1);
    BARRIER_VM();
  }

  // epilogue: C[row=(lane>>4)*4+r][col=lane&15]
  #pragma unroll
  for (int nt = 0; nt < 2; ++nt) {
    const int n = n0 + wn * 32 + nt * 16 + l15;
    const float bb = bias[n];
    #pragma unroll
    for (int mt = 0; mt < 4; ++mt) {
      #pragma unroll
      for (int r = 0; r < 4; ++r) {
        const int m = m0 + wm * 64 + mt * 16 + lg * 4 + r;
        float v = acc[mt][nt][r] + bb;
        if (mode == 3) {
          const int cm = isDiff ? (m / ND) : ((m - MD) >> 4);
          v -= Xmean[(size_t)cm * DD + n];
        }
        if (ResB) v += b2f(ResB[(size_t)m * DD + n]);
        OutB[(size_t)m * DD + n] = f2b(v);
      }
    }
  }
}

// ---------------------------------------------------------------------------
// 16x16 MFMA flash attention (round-7/9 proven body). 256 thr / 4 waves x
// 16 q-rows, kv-tile 32, single-buffered K/Pt staging.
// LDS = EXACTLY 40960 B (epilogue pitch 640, overlaying staging) ->
// 4 blocks/CU = 16 waves/CU (VGPR 108: 4x108=432 <= 512/SIMD).
// K-operand = P rows; V-operand = P^T. Swapped QK^T; T13 defer-max (THR=8);
// in-reg P pack via 8 shfl; O^T = mfma16(Pt_frag, P_frag); setprio on MFMA.
// ---------------------------------------------------------------------------
__global__ __launch_bounds__(256, 2) void attn16(
    const unsigned short* __restrict__ Qg, const unsigned short* __restrict__ Pk,
    const unsigned short* __restrict__ Pt, unsigned short* __restrict__ Ob,
    const int qRows,      // rows per class: 1008 | 16
    const int kPitch,     // rows per class in Pk: 1008 | 16
    const int vtPitch,    // P^T kv pitch: 1024 | 32
    const int nKT, const int validKV, const int bpc, const int qTiles)
{
  __shared__ __align__(16) char smem[40960];      // staging 40960 | epi 4x10240
  const int t = threadIdx.x;
  const int wid = t >> 6, lane = t & 63;
  const int l15 = lane & 15, lg = lane >> 4;

  int bx = blockIdx.x;
  const int nwg = gridDim.x;
  if ((nwg & 7) == 0) bx = (bx & 7) * (nwg >> 3) + (bx >> 3);   // XCD swizzle
  const int cls  = bx / bpc;
  const int blkq = bx - cls * bpc;
  const int qt0 = blkq * 4 + wid;
  const bool wValid = qt0 < qTiles;
  const int qt = wValid ? qt0 : qTiles - 1;

  // Q fragments (B operand): lane holds Q[q=l15][kd = kc*32 + lg*8 + j]
  short8 qf[10];
  {
    const unsigned short* qrow = Qg + ((size_t)cls * qRows + qt * 16 + l15) * DD;
    #pragma unroll
    for (int kc = 0; kc < 10; ++kc) qf[kc] = *(const short8*)(qrow + kc * 32 + lg * 8);
  }

  floatx4 o[20];
  #pragma unroll
  for (int i = 0; i < 20; ++i) o[i] = (floatx4){0.f, 0.f, 0.f, 0.f};
  float mrun = -1e30f, lsum = 0.f;
  const float scale = 0.05590169943749474f;       // 1/sqrt(320)

  for (int kt = 0; kt < nKT; ++kt) {
    // ---- stage K = P rows [32 kv][320 d] and V = P^T [320 d][32 kv] ----
    __syncthreads();
    #pragma unroll
    for (int it = 0; it < 5; ++it) {
      const int L = it * 256 + t;                 // 16B chunk
      const int r = L / 40, c = L - (L / 40) * 40;
      const int cl = (c & ~7) | ((c & 7) ^ (r & 7));
      gl_lds16(Pk + ((size_t)cls * kPitch + kt * 32 + r) * DD + cl * 8, smem + L * 16);
    }
    #pragma unroll
    for (int it = 0; it < 5; ++it) {
      const int L = it * 256 + t;
      const int d = L >> 2, c = L & 3;
      const int cl = c ^ ((d >> 1) & 3);
      gl_lds16(Pt + ((size_t)cls * DD + d) * vtPitch + kt * 32 + cl * 8,
               smem + 20480 + L * 16);
    }
    __syncthreads();

    // ---- S^T = K @ Q^T : lane holds St[kv=st*16+lg*4+r][q=l15] ----
    floatx4 st0 = (floatx4){0.f,0.f,0.f,0.f}, st1 = (floatx4){0.f,0.f,0.f,0.f};
    __builtin_amdgcn_s_setprio(1);
    #pragma unroll
    for (int kc = 0; kc < 10; ++kc) {
      const int c = kc * 4 + lg;
      const int cl = (c & ~7) | ((c & 7) ^ (l15 & 7));
      const short8 k0f = *(const short8*)(smem + l15 * 640 + cl * 16);
      const short8 k1f = *(const short8*)(smem + (16 + l15) * 640 + cl * 16);
      st0 = mfma16(k0f, qf[kc], st0);
      st1 = mfma16(k1f, qf[kc], st1);
    }
    __builtin_amdgcn_s_setprio(0);

    // ---- online softmax ----
    float s[8];
    #pragma unroll
    for (int r = 0; r < 4; ++r) { s[r] = st0[r] * scale; s[4 + r] = st1[r] * scale; }
    const int kvb = kt * 32 + lg * 4;
    #pragma unroll
    for (int r = 0; r < 4; ++r) {
      if (kvb + r      >= validKV) s[r]     = -1e30f;
      if (kvb + 16 + r >= validKV) s[4 + r] = -1e30f;
    }
    float mt_ = s[0];
    #pragma unroll
    for (int i = 1; i < 8; ++i) mt_ = fmaxf(mt_, s[i]);
    mt_ = fmaxf(mt_, __shfl_xor(mt_, 16));
    mt_ = fmaxf(mt_, __shfl_xor(mt_, 32));
    if (!__all(mt_ - mrun <= 8.0f)) {             // T13 defer-max (THR=8)
      const float newm = fmaxf(mrun, mt_);
      const float alpha = __expf(mrun - newm);
      lsum *= alpha;
      #pragma unroll
      for (int i = 0; i < 20; ++i) {
        o[i][0] *= alpha; o[i][1] *= alpha; o[i][2] *= alpha; o[i][3] *= alpha;
      }
      mrun = newm;
    }
    float p[8]; float rs = 0.f;
    #pragma unroll
    for (int i = 0; i < 8; ++i) { p[i] = __expf(s[i] - mrun); rs += p[i]; }
    rs += __shfl_xor(rs, 16);
    rs += __shfl_xor(rs, 32);
    lsum += rs;

    // ---- pack P to bf16, redistribute to PV B-frag ----
    const unsigned int pk00 = pk2(p[0], p[1]), pk01 = pk2(p[2], p[3]);
    const unsigned int pk10 = pk2(p[4], p[5]), pk11 = pk2(p[6], p[7]);
    const int src0 = l15 + ((lane >> 4) & 1) * 32;
    const int src1 = src0 + 16;
    const int y0 = __shfl((int)pk00, src0), y1 = __shfl((int)pk01, src0);
    const int y2 = __shfl((int)pk00, src1), y3 = __shfl((int)pk01, src1);
    const int z0 = __shfl((int)pk10, src0), z1 = __shfl((int)pk11, src0);
    const int z2 = __shfl((int)pk10, src1), z3 = __shfl((int)pk11, src1);
    const bool hi = lane >= 32;                   // subtile select (kv>=16)
    union { i32x4 w; short8 v; } pf;
    pf.w[0] = hi ? z0 : y0; pf.w[1] = hi ? z1 : y1;
    pf.w[2] = hi ? z2 : y2; pf.w[3] = hi ? z3 : y3;

    // ---- O^T += Pt_tile @ P : 20 d-tiles ----
    const int vswz = (l15 >> 1) & 3;
    __builtin_amdgcn_s_setprio(1);
    #pragma unroll
    for (int dt = 0; dt < 20; ++dt) {
      const int d = dt * 16 + l15;
      const short8 a = *(const short8*)(smem + 20480 + d * 64 + ((lg ^ vswz) << 4));
      o[dt] = mfma16(a, pf.v, o[dt]);
    }
    __builtin_amdgcn_s_setprio(0);
  }

  // ---- epilogue: O^T frags -> per-wave LDS [16q][320 bf16, pitch 640B] ----
  const float invl = 1.f / lsum;
  __syncthreads();
  char* ep = smem + wid * 10240;
  #pragma unroll
  for (int dt = 0; dt < 20; ++dt) {
    const unsigned int w0 = pk2(o[dt][0] * invl, o[dt][1] * invl);
    const unsigned int w1 = pk2(o[dt][2] * invl, o[dt][3] * invl);
    *(unsigned int*)(ep + l15 * 640 + (dt * 16 + lg * 4) * 2)     = w0;
    *(unsigned int*)(ep + l15 * 640 + (dt * 16 + lg * 4 + 2) * 2) = w1;
  }
  __syncthreads();
  if (wValid) {
    #pragma unroll
    for (int it = 0; it < 10; ++it) {
      const int flat = it * 64 + lane;
      const int q = flat / 40, c = flat - (flat / 40) * 40;
      const i32x4 v = *(const i32x4*)(ep + q * 640 + c * 16);
      *(i32x4*)(Ob + ((size_t)cls * qRows + qt * 16 + q) * DD + c * 8) = v;
    }
  }
}

// ---------------------------------------------------------------------------
// P [cls][rowsP][320] bf16 -> Pt [cls][320][vtPitch] bf16, zero-padded kv.
// ---------------------------------------------------------------------------
__global__ __launch_bounds__(256) void transpose_p(
    const unsigned short* __restrict__ P, unsigned short* __restrict__ PtG,
    const int rowsP, const int vtPitch, const int kvTilesPerCls)
{
  __shared__ __align__(16) unsigned short Ls[64 * 72];
  const int t = threadIdx.x;
  const int cls = blockIdx.x / kvTilesPerCls;
  const int kvt = blockIdx.x - cls * kvTilesPerCls;
  const int dt = blockIdx.y;
  #pragma unroll
  for (int i = 0; i < 2; ++i) {
    const int flat = t + i * 256;
    const int r = flat >> 3, c = flat & 7;
    const int kv = kvt * 64 + r;
    i32x4 v = {0, 0, 0, 0};
    if (kv < rowsP)
      v = *(const i32x4*)(P + ((size_t)cls * rowsP + kv) * DD + dt * 64 + c * 8);
    *(i32x4*)(&Ls[r * 72 + c * 8]) = v;
  }
  __syncthreads();
  #pragma unroll
  for (int i = 0; i < 2; ++i) {
    const int flat = t + i * 256;
    const int r2 = flat >> 3, c2 = flat & 7;
    if (kvt * 64 + c2 * 8 < vtPitch) {
      union { unsigned short e[8]; i32x4 v; } u;
      #pragma unroll
      for (int jj = 0; jj < 8; ++jj) u.e[jj] = Ls[(c2 * 8 + jj) * 72 + r2];
      *(i32x4*)(PtG + ((size_t)cls * DD + dt * 64 + r2) * vtPitch + kvt * 64 + c2 * 8) = u.v;
    }
  }
}

// ---------------------------------------------------------------------------
// Merged weight prep (grid.z selects task):
//  z=0: BtS = (Wsame)^T bf16   z=1: BtD = (Wdiff)^T bf16
//  z=2: BtG[n][k] = sum_m Wk[n,m] Wq[k,m]   z=3: BtVF[n][k] = sum_m Wfc[m,n] Wv[k,m]
// ---------------------------------------------------------------------------
__global__ __launch_bounds__(256) void wprep(
    const float* __restrict__ Wsame, const float* __restrict__ Wdiff,
    const float* __restrict__ Wk, const float* __restrict__ Wq,
    const float* __restrict__ Wfc, const float* __restrict__ Wv,
    unsigned short* __restrict__ BtS, unsigned short* __restrict__ BtD,
    unsigned short* __restrict__ BtG, unsigned short* __restrict__ BtVF)
{
  __shared__ float Ls[64 * 68];
  const int t = threadIdx.x;
  const int z = blockIdx.z;
  if (z < 2) {                                   // transpose fp32 -> bf16^T
    const float* W = z ? Wdiff : Wsame;
    unsigned short* Wt = z ? BtD : BtS;
    const int k0 = blockIdx.x * 64, n0 = blockIdx.y * 64;
    #pragma unroll
    for (int i = 0; i < 4; ++i) {
      const int flat = t + i * 256;
      const int r = flat >> 4, c = (flat & 15) * 4;
      *(float4*)&Ls[r * 68 + c] = *(const float4*)(W + (size_t)(k0 + r) * DD + n0 + c);
    }
    __syncthreads();
    #pragma unroll
    for (int j = 0; j < 2; ++j) {
      const int flat = t + j * 256;
      const int r2 = flat >> 3, c2 = flat & 7;
      union { unsigned short e[8]; i32x4 v; } u;
      #pragma unroll
      for (int jj = 0; jj < 8; ++jj) u.e[jj] = f2b(Ls[(c2 * 8 + jj) * 68 + r2]);
      *(i32x4*)(Wt + (size_t)(n0 + r2) * DD + k0 + c2 * 8) = u.v;
    }
  } else {                                       // weight product
    const int trL = (z == 3);
    const float* L = trL ? Wfc : Wk;
    const float* R = trL ? Wv : Wq;
    float* Lsm = Ls;                // [16][68]
    float* Rsm = Ls + 16 * 68;
    const int n0 = blockIdx.x * 64, k0 = blockIdx.y * 64;
    const int tn4 = (t & 15) * 4, tk4 = (t >> 4) * 4;
    float acc[4][4] = {};
    for (int ms = 0; ms < DD; ms += 16) {
      const int lr = t >> 4, lc = (t & 15);
      #pragma unroll
      for (int i = 0; i < 4; ++i) {
        const int nn = lc * 4 + i;
        Lsm[lr * 68 + nn] = trL ? L[(size_t)(ms + lr) * DD + n0 + nn]
                                : L[(size_t)(n0 + nn) * DD + ms + lr];
        Rsm[lr * 68 + nn] = R[(size_t)(k0 + nn) * DD + ms + lr];
      }
      __syncthreads();
      #pragma unroll
      for (int mm = 0; mm < 16; ++mm) {
        float la[4], rb[4];
        #pragma unroll
        for (int i = 0; i < 4; ++i) { la[i] = Lsm[mm * 68 + tn4 + i]; rb[i] = Rsm[mm * 68 + tk4 + i]; }
        #pragma unroll
        for (int i = 0; i < 4; ++i)
          #pragma unroll
          for (int j = 0; j < 4; ++j) acc[i][j] += la[i] * rb[j];
      }
      __syncthreads();
    }
    #pragma unroll
    for (int i = 0; i < 4; ++i)
      #pragma unroll
      for (int j = 0; j < 4; ++j)
        ((z == 2) ? BtG : BtVF)[(size_t)(n0 + tn4 + i) * DD + k0 + tk4 + j] = f2b(acc[i][j]);
  }
}

// v[n] = sum_m Wk[n,m] bq[m];  bvf[n] = sum_m Wfc[m,n] bv[m] + bfc[n]
__global__ __launch_bounds__(640) void wbias(
    const float* __restrict__ Wk, const float* __restrict__ bq,
    const float* __restrict__ Wfc, const float* __restrict__ bv,
    const float* __restrict__ bfc, float* __restrict__ v, float* __restrict__ bvf)
{
  const int t = threadIdx.x;
  if (t < DD) {
    float a = 0.f;
    for (int m = 0; m < DD; ++m) a += Wk[(size_t)t * DD + m] * bq[m];
    v[t] = a;
  } else if (t < 2 * DD) {
    const int n = t - DD;
    float a = 0.f;
    for (int m = 0; m < DD; ++m) a += Wfc[(size_t)m * DD + n] * bv[m];
    bvf[n] = a + bfc[n];
  }
}

// ---------------------------------------------------------------------------
// Per-row LayerNorm + logit (bf16 in), 1 wave/row, merged M=65536.
// ---------------------------------------------------------------------------
__global__ __launch_bounds__(256) void ln_logit(
    const unsigned short* __restrict__ X, const float* __restrict__ gam,
    const float* __restrict__ bet, const float* __restrict__ Wout,
    const float* __restrict__ bout, float* __restrict__ logits, const int M)
{
  const int row = blockIdx.x * 4 + (threadIdx.x >> 6);
  if (row >= M) return;
  const int lane = threadIdx.x & 63;
  const unsigned short* x = X + (size_t)row * DD;
  float v[5]; float s = 0.f;
  #pragma unroll
  for (int i = 0; i < 5; ++i) { v[i] = b2f(x[lane + 64 * i]); s += v[i]; }
  #pragma unroll
  for (int off = 32; off; off >>= 1) s += __shfl_xor(s, off);
  const float mu = s * (1.f / DD);
  float q = 0.f;
  #pragma unroll
  for (int i = 0; i < 5; ++i) { const float d = v[i] - mu; q += d * d; }
  #pragma unroll
  for (int off = 32; off; off >>= 1) q += __shfl_xor(q, off);
  const float inv = rsqrtf(q * (1.f / DD) + LN_EPS);
  float lg = 0.f;
  #pragma unroll
  for (int i = 0; i < 5; ++i) {
    const int k = lane + 64 * i;
    lg += (gam[k] * (v[i] - mu) * inv + bet[k]) * Wout[k];
  }
  #pragma unroll
  for (int off = 32; off; off >>= 1) lg += __shfl_xor(lg, off);
  if (lane == 0) logits[row] = lg + bout[0];
}

// ---------------------------------------------------------------------------
// Final: per-class softmax over logits, weighted mean of P (bf16).
// ---------------------------------------------------------------------------
__global__ __launch_bounds__(320) void final_reduce(
    const float* __restrict__ logits_s, const float* __restrict__ logits_d,
    const unsigned short* __restrict__ Ps, const unsigned short* __restrict__ Pd,
    float* __restrict__ out)
{
  const int c = blockIdx.x;
  const int t = threadIdx.x;
  __shared__ float w[16 + ND];
  __shared__ float red[5];
  if (t < 16) w[t] = logits_s[c * 16 + t];
  for (int j = t; j < ND; j += 320) w[16 + j] = logits_d[c * ND + j];
  __syncthreads();
  if (t == 0) {
    float mx = w[0];
    #pragma unroll
    for (int i = 1; i < 16; ++i) mx = fmaxf(mx, w[i]);
    float ssum = 0.f;
    #pragma unroll
    for (int i = 0; i < 16; ++i) { const float e = __expf(w[i] - mx); w[i] = e; ssum += e; }
    const float inv = 1.f / ssum;
    #pragma unroll
    for (int i = 0; i < 16; ++i) w[i] *= inv;
  }
  float lm = -1e30f;
  for (int j = t; j < ND; j += 320) lm = fmaxf(lm, w[16 + j]);
  #pragma unroll
  for (int off = 32; off; off >>= 1) lm = fmaxf(lm, __shfl_xor(lm, off));
  if ((t & 63) == 0) red[t >> 6] = lm;
  __syncthreads();
  const float mx = fmaxf(fmaxf(fmaxf(red[0], red[1]), fmaxf(red[2], red[3])), red[4]);
  float ls = 0.f;
  for (int j = t; j < ND; j += 320) { const float e = __expf(w[16 + j] - mx); w[16 + j] = e; ls += e; }
  #pragma unroll
  for (int off = 32; off; off >>= 1) ls += __shfl_xor(ls, off);
  __syncthreads();
  if ((t & 63) == 0) red[t >> 6] = ls;
  __syncthreads();
  const float inv = 1.f / (red[0] + red[1] + red[2] + red[3] + red[4]);
  for (int j = t; j < ND; j += 320) w[16 + j] *= inv;
  __syncthreads();
  float acc = 0.f;
  const unsigned short* Psc = Ps + (size_t)c * SHOT * DD + t;
  const unsigned short* Pdc = Pd + (size_t)c * ND * DD + t;
  #pragma unroll 4
  for (int i = 0; i < 16; ++i) acc += w[i] * b2f(Psc[(size_t)i * DD]);
  for (int j = 0; j < ND; ++j) acc += w[16 + j] * b2f(Pdc[(size_t)j * DD]);
  out[c * DD + t] = acc * (1.f / 1024.f);
}

// ---------------------------------------------------------------------------
extern "C" void kernel_launch(void* const* d_in, const int* in_sizes, int n_in,
                              void* d_out, int out_size, void* d_ws, size_t ws_size,
                              hipStream_t stream)
{
  const float* xmean = (const float*)d_in[0];
  const float* x     = (const float*)d_in[1];
  const float* Wsame = (const float*)d_in[2];
  const float* bsame = (const float*)d_in[3];
  const float* Wdiff = (const float*)d_in[4];
  const float* bdiff = (const float*)d_in[5];
  const float* Wq    = (const float*)d_in[6];
  const float* bq    = (const float*)d_in[7];
  const float* Wk    = (const float*)d_in[8];
  const float* bk    = (const float*)d_in[9];   (void)bk; // row-const in softmax
  const float* Wv    = (const float*)d_in[10];
  const float* bv    = (const float*)d_in[11];
  const float* Wfc   = (const float*)d_in[12];
  const float* bfc   = (const float*)d_in[13];
  const float* lng   = (const float*)d_in[14];
  const float* lnb   = (const float*)d_in[15];
  const float* Wout  = (const float*)d_in[16];
  const float* boutp = (const float*)d_in[17];
  float* outp = (float*)d_out;

  char* base = (char*)d_ws;
  size_t off = 0;
  auto alloc = [&](size_t bytes) { char* p = base + off; off += (bytes + 255) & ~(size_t)255; return p; };

  const size_t WB = (size_t)DD * DD * 2;
  unsigned short* BtS  = (unsigned short*)alloc(WB);
  unsigned short* BtD  = (unsigned short*)alloc(WB);
  unsigned short* BtG  = (unsigned short*)alloc(WB);
  unsigned short* BtVF = (unsigned short*)alloc(WB);
  float* vbias = (float*)alloc(DD * 4);
  float* bvf   = (float*)alloc(DD * 4);
  // merged row space: [0,MD) diff (per class 1008), [MD,MT) same (per class 16)
  unsigned short* P_b  = (unsigned short*)alloc((size_t)MT * DD * 2);
  unsigned short* Qg_b = (unsigned short*)alloc((size_t)MT * DD * 2);  // also F out
  unsigned short* O_b  = (unsigned short*)alloc((size_t)MT * DD * 2);
  unsigned short* PtD  = (unsigned short*)alloc((size_t)CC * DD * 1024 * 2);
  unsigned short* PtS  = (unsigned short*)alloc((size_t)CC * DD * 32 * 2);
  float* logits = (float*)alloc((size_t)MT * 4);

  const dim3 blk(256);
  // ---- weight prep (2 dispatches) ----
  wprep<<<dim3(5, 5, 4), blk, 0, stream>>>(Wsame, Wdiff, Wk, Wq, Wfc, Wv,
                                           BtS, BtD, BtG, BtVF);
  wbias<<<dim3(1), dim3(640), 0, stream>>>(Wk, bq, Wfc, bv, bfc, vbias, bvf);

  // ---- P = branch-projected & centered, both branches in one dispatch ----
  const dim3 gAll(MT / 128, 5);
  gemm_mfma<<<gAll, blk, 0, stream>>>(nullptr, x, xmean, 3, BtD, BtS,
                                      bdiff, bsame, P_b, nullptr);
  // ---- P^T for PV (diff: pitch 1024; same: pitch 32) ----
  transpose_p<<<dim3(CC * 16, 5), blk, 0, stream>>>(P_b, PtD, ND, 1024, 16);
  transpose_p<<<dim3(CC, 5), blk, 0, stream>>>(P_b + (size_t)MD * DD, PtS, 16, 32, 1);
  // ---- Qg = P @ G + vbias (merged) ----
  gemm_mfma<<<gAll, blk, 0, stream>>>(P_b, nullptr, nullptr, 0, BtG, nullptr,
                                      vbias, nullptr, Qg_b, nullptr);
  // ---- attention (diff + same) ----
  attn16<<<dim3(CC * 16), blk, 0, stream>>>(Qg_b, P_b, PtD, O_b,
                                            ND, ND, 1024, 32, ND, 16, 63);
  attn16<<<dim3(CC), blk, 0, stream>>>(Qg_b + (size_t)MD * DD, P_b + (size_t)MD * DD,
                                       PtS, O_b + (size_t)MD * DD,
                                       16, 16, 32, 1, 16, 1, 1);
  // ---- F = O @ (Wv Wfc) + bvf + P (merged) ----
  gemm_mfma<<<gAll, blk, 0, stream>>>(O_b, nullptr, nullptr, 0, BtVF, nullptr,
                                      bvf, nullptr, Qg_b, P_b);
  // ---- LN + logits (merged) ----
  ln_logit<<<dim3(MT / 4), blk, 0, stream>>>(Qg_b, lng, lnb, Wout, boutp, logits, MT);
  // ---- final softmax-weighted mean ----
  final_reduce<<<dim3(CC), dim3(320), 0, stream>>>(logits + MD, logits,
                                                   P_b + (size_t)MD * DD, P_b, outp);
}

// Round 12
// 478.142 us; speedup vs baseline: 1.4632x; 1.0290x over previous
//
#include <hip/hip_runtime.h>

#define CC   64
#define SHOT 16
#define DD   320
#define ND   1008            // (CC-1)*SHOT
#define MS   (CC * SHOT)     // 1024
#define MD   (CC * ND)       // 64512
#define MT   (MD + MS)       // 65536 = 512*128
#define LN_EPS 1e-5f

typedef __attribute__((ext_vector_type(8)))  short short8;    // 8 bf16 = 4 VGPR
typedef __attribute__((ext_vector_type(4)))  float floatx4;
typedef __attribute__((ext_vector_type(4)))  int i32x4;

__device__ __forceinline__ unsigned short f2b(float f) {     // fp32 -> bf16 RNE
  union { float f; unsigned int u; } v; v.f = f;
  unsigned int r = v.u + 0x7FFFu + ((v.u >> 16) & 1u);
  return (unsigned short)(r >> 16);
}
__device__ __forceinline__ float b2f(unsigned short b) {
  union { unsigned int u; float f; } v; v.u = ((unsigned int)b) << 16; return v.f;
}
__device__ __forceinline__ unsigned int pk2(float a, float b) {
  return (unsigned int)f2b(a) | ((unsigned int)f2b(b) << 16);
}
__device__ __forceinline__ void gl_lds16(const void* g, void* l) {
  __builtin_amdgcn_global_load_lds(
      (const __attribute__((address_space(1))) unsigned int*)g,
      (__attribute__((address_space(3))) unsigned int*)l, 16, 0, 0);
}
__device__ __forceinline__ floatx4 mfma16(short8 a, short8 b, floatx4 c) {
  return __builtin_amdgcn_mfma_f32_16x16x32_bf16(a, b, c, 0, 0, 0);
}
#define BARRIER_VM()  do { asm volatile("s_waitcnt vmcnt(0) lgkmcnt(0)" ::: "memory"); \
                           __builtin_amdgcn_s_barrier(); \
                           __builtin_amdgcn_sched_barrier(0); } while (0)

// ---------------------------------------------------------------------------
// MFMA GEMM over the MERGED row space [0,65536): rows <MD are diff-branch,
// rows >=MD are same-branch. BM=128 BN=64 BK=64, 4 waves (2x2).
// mode 0: A bf16 passthrough, weights BtDiff/biasDiff for ALL rows,
//         optional residual ResB, no mean-sub.
// mode 3: P-build. diff: A=xmean[c]-x[gather], W=BtDiff,b=biasDiff;
//         same: A=x[ls]-xmean[ls/16], W=BtSame,b=biasSame. Epilogue subtracts
//         xmean[class][n] for both regions.
// ---------------------------------------------------------------------------
__global__ __launch_bounds__(256, 2) void gemm_mfma(
    const unsigned short* __restrict__ A,
    const float* __restrict__ Xg, const float* __restrict__ Xmean,
    const int mode,
    const unsigned short* __restrict__ BtDiff,
    const unsigned short* __restrict__ BtSame,
    const float* __restrict__ biasDiff, const float* __restrict__ biasSame,
    unsigned short* __restrict__ OutB,
    const unsigned short* __restrict__ ResB)
{
  __shared__ __align__(16) unsigned short As[2][128 * 64];
  __shared__ __align__(16) unsigned short Bs[2][64 * 64];
  const int t  = threadIdx.x;
  const int m0 = blockIdx.x * 128;
  const int n0 = blockIdx.y * 64;
  const int wid = t >> 6, lane = t & 63;
  const int wm = wid >> 1, wn = wid & 1;
  const int l15 = lane & 15, lg = lane >> 4;

  const bool isDiff = (m0 < MD);
  const unsigned short* Bt = (mode == 3 && !isDiff) ? BtSame : BtDiff;
  const float* bias = (mode == 3 && !isDiff) ? biasSame : biasDiff;

  const int ra = t >> 1, kh = t & 1;
  const float* aptr = nullptr; const float* mptr = nullptr;
  float sa = 1.f;
  if (mode == 3) {
    const int am = m0 + ra;
    if (isDiff) {
      const int c = am / ND, j = am - c * ND;
      const int oi = j >> 4, s = j & 15;
      const int oc = (oi < c) ? oi : oi + 1;
      aptr = Xg + (size_t)(oc * SHOT + s) * DD;
      mptr = Xmean + (size_t)c * DD;
      sa = -1.f;
    } else {
      const int ls = am - MD;
      aptr = Xg + (size_t)ls * DD;
      mptr = Xmean + (size_t)(ls >> 4) * DD;
      sa = 1.f;
    }
  }

  floatx4 acc[4][2];
  #pragma unroll
  for (int i = 0; i < 4; ++i)
    #pragma unroll
    for (int j = 0; j < 2; ++j) acc[i][j] = (floatx4){0.f, 0.f, 0.f, 0.f};

  auto stage = [&](int ks, int bufi) {
    const int k0 = ks * 64;
    #pragma unroll
    for (int it = 0; it < 2; ++it) {               // B tile 64x64
      const int L = it * 256 + t;
      const int r = L >> 3, cs = L & 7;
      const int cl = cs ^ (r & 7);
      gl_lds16(Bt + (size_t)(n0 + r) * DD + k0 + cl * 8, &Bs[bufi][0] + L * 8);
    }
    if (mode == 0) {
      #pragma unroll
      for (int it = 0; it < 4; ++it) {             // A tile 128x64
        const int L = it * 256 + t;
        const int r = L >> 3, cs = L & 7;
        const int cl = cs ^ (r & 7);
        gl_lds16(A + (size_t)(m0 + r) * DD + k0 + cl * 8, &As[bufi][0] + L * 8);
      }
    } else {                                        // fp32 gather+sub+cvt
      const int kb2 = k0 + kh * 32;
      #pragma unroll
      for (int i = 0; i < 4; ++i) {
        const float4 x0  = *(const float4*)(aptr + kb2 + i * 8);
        const float4 x1  = *(const float4*)(aptr + kb2 + i * 8 + 4);
        const float4 mv0 = *(const float4*)(mptr + kb2 + i * 8);
        const float4 mv1 = *(const float4*)(mptr + kb2 + i * 8 + 4);
        i32x4 w;
        w[0] = (int)pk2(sa * (x0.x - mv0.x), sa * (x0.y - mv0.y));
        w[1] = (int)pk2(sa * (x0.z - mv0.z), sa * (x0.w - mv0.w));
        w[2] = (int)pk2(sa * (x1.x - mv1.x), sa * (x1.y - mv1.y));
        w[3] = (int)pk2(sa * (x1.z - mv1.z), sa * (x1.w - mv1.w));
        const int c  = kh * 4 + i;
        const int cw = c ^ (ra & 7);
        *(i32x4*)((char*)&As[bufi][0] + ra * 128 + cw * 16) = w;
      }
    }
  };

  auto compute = [&](int bufi) {
    #pragma unroll
    for (int kc = 0; kc < 2; ++kc) {
      short8 af[4], bf[2];
      #pragma unroll
      for (int mt = 0; mt < 4; ++mt) {
        const int row = wm * 64 + mt * 16 + l15;
        const int cs  = (kc * 4 + lg) ^ (row & 7);
        af[mt] = *(const short8*)((const char*)&As[bufi][0] + row * 128 + cs * 16);
      }
      #pragma unroll
      for (int nt = 0; nt < 2; ++nt) {
        const int row = wn * 32 + nt * 16 + l15;
        const int cs  = (kc * 4 + lg) ^ (row & 7);
        bf[nt] = *(const short8*)((const char*)&Bs[bufi][0] + row * 128 + cs * 16);
      }
      #pragma unroll
      for (int mt = 0; mt < 4; ++mt)
        #pragma unroll
        for (int nt = 0; nt < 2; ++nt)
          acc[mt][nt] = mfma16(af[mt], bf[nt], acc[mt][nt]);
    }
  };

  stage(0, 0);
  BARRIER_VM();
  for (int ks = 0; ks < 5; ++ks) {
    if (ks + 1 < 5) stage(ks + 1, (ks + 1) & 1);
    compute(ks & 1);
    BARRIER_VM();
  }

  // epilogue: C[row=(lane>>4)*4+r][col=lane&15]
  #pragma unroll
  for (int nt = 0; nt < 2; ++nt) {
    const int n = n0 + wn * 32 + nt * 16 + l15;
    const float bb = bias[n];
    #pragma unroll
    for (int mt = 0; mt < 4; ++mt) {
      #pragma unroll
      for (int r = 0; r < 4; ++r) {
        const int m = m0 + wm * 64 + mt * 16 + lg * 4 + r;
        float v = acc[mt][nt][r] + bb;
        if (mode == 3) {
          const int cm = isDiff ? (m / ND) : ((m - MD) >> 4);
          v -= Xmean[(size_t)cm * DD + n];
        }
        if (ResB) v += b2f(ResB[(size_t)m * DD + n]);
        OutB[(size_t)m * DD + n] = f2b(v);
      }
    }
  }
}

// ---------------------------------------------------------------------------
// 16x16 MFMA flash attention, merged regions: blocks [0,1024) diff (XCD
// swizzle with chunk LOCKED at 128 -> identical class->XCD map as the
// 1024-block dispatch), blocks [1024,1088) same (direct map, no swizzle).
// 256 thr / 4 waves x 16 q-rows, kv-tile 32, single-buffered staging,
// LDS 40960. Epilogue XOR-swizzled (byte ^= (q&7)<<4) -> 2-way max.
// ---------------------------------------------------------------------------
__global__ __launch_bounds__(256, 2) void attn16(
    const unsigned short* __restrict__ Qall, const unsigned short* __restrict__ Pall,
    const unsigned short* __restrict__ PtD, const unsigned short* __restrict__ PtS,
    unsigned short* __restrict__ Oall)
{
  __shared__ __align__(16) char smem[40960];      // staging 40960 | epi 4x10240
  const int t = threadIdx.x;
  const int wid = t >> 6, lane = t & 63;
  const int l15 = lane & 15, lg = lane >> 4;

  int bx = blockIdx.x;
  const unsigned short *Qg, *Pk, *Pt; unsigned short* Ob;
  int cls, blkq, qRows, kPitch, vtPitch, nKT, validKV, qTiles;
  if (bx < 1024) {
    bx = (bx & 7) * 128 + (bx >> 3);              // chunk 128: classes 8x..8x+7 per XCD
    cls = bx >> 4; blkq = bx & 15;
    Qg = Qall; Pk = Pall; Pt = PtD; Ob = Oall;
    qRows = ND; kPitch = ND; vtPitch = 1024; nKT = 32; validKV = ND; qTiles = 63;
  } else {
    cls = bx - 1024; blkq = 0;
    Qg = Qall + (size_t)MD * DD; Pk = Pall + (size_t)MD * DD;
    Pt = PtS; Ob = Oall + (size_t)MD * DD;
    qRows = 16; kPitch = 16; vtPitch = 32; nKT = 1; validKV = 16; qTiles = 1;
  }
  const int qt0 = blkq * 4 + wid;
  const bool wValid = qt0 < qTiles;
  const int qt = wValid ? qt0 : qTiles - 1;

  // Q fragments (B operand): lane holds Q[q=l15][kd = kc*32 + lg*8 + j]
  short8 qf[10];
  {
    const unsigned short* qrow = Qg + ((size_t)cls * qRows + qt * 16 + l15) * DD;
    #pragma unroll
    for (int kc = 0; kc < 10; ++kc) qf[kc] = *(const short8*)(qrow + kc * 32 + lg * 8);
  }

  floatx4 o[20];
  #pragma unroll
  for (int i = 0; i < 20; ++i) o[i] = (floatx4){0.f, 0.f, 0.f, 0.f};
  float mrun = -1e30f, lsum = 0.f;
  const float scale = 0.05590169943749474f;       // 1/sqrt(320)

  for (int kt = 0; kt < nKT; ++kt) {
    // ---- stage K = P rows [32 kv][320 d] and V = P^T [320 d][32 kv] ----
    __syncthreads();
    #pragma unroll
    for (int it = 0; it < 5; ++it) {
      const int L = it * 256 + t;                 // 16B chunk
      const int r = L / 40, c = L - (L / 40) * 40;
      const int cl = (c & ~7) | ((c & 7) ^ (r & 7));
      gl_lds16(Pk + ((size_t)cls * kPitch + kt * 32 + r) * DD + cl * 8, smem + L * 16);
    }
    #pragma unroll
    for (int it = 0; it < 5; ++it) {
      const int L = it * 256 + t;
      const int d = L >> 2, c = L & 3;
      const int cl = c ^ ((d >> 1) & 3);
      gl_lds16(Pt + ((size_t)cls * DD + d) * vtPitch + kt * 32 + cl * 8,
               smem + 20480 + L * 16);
    }
    __syncthreads();

    // ---- S^T = K @ Q^T : lane holds St[kv=st*16+lg*4+r][q=l15] ----
    floatx4 st0 = (floatx4){0.f,0.f,0.f,0.f}, st1 = (floatx4){0.f,0.f,0.f,0.f};
    __builtin_amdgcn_s_setprio(1);
    #pragma unroll
    for (int kc = 0; kc < 10; ++kc) {
      const int c = kc * 4 + lg;
      const int cl = (c & ~7) | ((c & 7) ^ (l15 & 7));
      const short8 k0f = *(const short8*)(smem + l15 * 640 + cl * 16);
      const short8 k1f = *(const short8*)(smem + (16 + l15) * 640 + cl * 16);
      st0 = mfma16(k0f, qf[kc], st0);
      st1 = mfma16(k1f, qf[kc], st1);
    }
    __builtin_amdgcn_s_setprio(0);

    // ---- online softmax ----
    float s[8];
    #pragma unroll
    for (int r = 0; r < 4; ++r) { s[r] = st0[r] * scale; s[4 + r] = st1[r] * scale; }
    const int kvb = kt * 32 + lg * 4;
    #pragma unroll
    for (int r = 0; r < 4; ++r) {
      if (kvb + r      >= validKV) s[r]     = -1e30f;
      if (kvb + 16 + r >= validKV) s[4 + r] = -1e30f;
    }
    float mt_ = s[0];
    #pragma unroll
    for (int i = 1; i < 8; ++i) mt_ = fmaxf(mt_, s[i]);
    mt_ = fmaxf(mt_, __shfl_xor(mt_, 16));
    mt_ = fmaxf(mt_, __shfl_xor(mt_, 32));
    if (!__all(mt_ - mrun <= 8.0f)) {             // T13 defer-max (THR=8)
      const float newm = fmaxf(mrun, mt_);
      const float alpha = __expf(mrun - newm);
      lsum *= alpha;
      #pragma unroll
      for (int i = 0; i < 20; ++i) {
        o[i][0] *= alpha; o[i][1] *= alpha; o[i][2] *= alpha; o[i][3] *= alpha;
      }
      mrun = newm;
    }
    float p[8]; float rs = 0.f;
    #pragma unroll
    for (int i = 0; i < 8; ++i) { p[i] = __expf(s[i] - mrun); rs += p[i]; }
    rs += __shfl_xor(rs, 16);
    rs += __shfl_xor(rs, 32);
    lsum += rs;

    // ---- pack P to bf16, redistribute to PV B-frag ----
    const unsigned int pk00 = pk2(p[0], p[1]), pk01 = pk2(p[2], p[3]);
    const unsigned int pk10 = pk2(p[4], p[5]), pk11 = pk2(p[6], p[7]);
    const int src0 = l15 + ((lane >> 4) & 1) * 32;
    const int src1 = src0 + 16;
    const int y0 = __shfl((int)pk00, src0), y1 = __shfl((int)pk01, src0);
    const int y2 = __shfl((int)pk00, src1), y3 = __shfl((int)pk01, src1);
    const int z0 = __shfl((int)pk10, src0), z1 = __shfl((int)pk11, src0);
    const int z2 = __shfl((int)pk10, src1), z3 = __shfl((int)pk11, src1);
    const bool hi = lane >= 32;                   // subtile select (kv>=16)
    union { i32x4 w; short8 v; } pf;
    pf.w[0] = hi ? z0 : y0; pf.w[1] = hi ? z1 : y1;
    pf.w[2] = hi ? z2 : y2; pf.w[3] = hi ? z3 : y3;

    // ---- O^T += Pt_tile @ P : 20 d-tiles ----
    const int vswz = (l15 >> 1) & 3;
    __builtin_amdgcn_s_setprio(1);
    #pragma unroll
    for (int dt = 0; dt < 20; ++dt) {
      const int d = dt * 16 + l15;
      const short8 a = *(const short8*)(smem + 20480 + d * 64 + ((lg ^ vswz) << 4));
      o[dt] = mfma16(a, pf.v, o[dt]);
    }
    __builtin_amdgcn_s_setprio(0);
  }

  // ---- epilogue: per-wave LDS [16q][pitch 640B], XOR-swizzled (2-way max) ----
  const float invl = 1.f / lsum;
  __syncthreads();
  char* ep = smem + wid * 10240;
  const int qx = (l15 & 7) << 4;
  #pragma unroll
  for (int dt = 0; dt < 20; ++dt) {
    const unsigned int w0 = pk2(o[dt][0] * invl, o[dt][1] * invl);
    const unsigned int w1 = pk2(o[dt][2] * invl, o[dt][3] * invl);
    *(unsigned int*)(ep + l15 * 640 + (((dt * 16 + lg * 4) * 2) ^ qx))     = w0;
    *(unsigned int*)(ep + l15 * 640 + (((dt * 16 + lg * 4 + 2) * 2) ^ qx)) = w1;
  }
  __syncthreads();
  if (wValid) {
    #pragma unroll
    for (int it = 0; it < 10; ++it) {
      const int flat = it * 64 + lane;
      const int q = flat / 40, c = flat - (flat / 40) * 40;
      const i32x4 v = *(const i32x4*)(ep + q * 640 + ((c * 16) ^ ((q & 7) << 4)));
      *(i32x4*)(Ob + ((size_t)cls * qRows + qt * 16 + q) * DD + c * 8) = v;
    }
  }
}

// ---------------------------------------------------------------------------
// P [cls][rowsP][320] bf16 -> Pt [cls][320][vtPitch] bf16, zero-padded kv.
// ---------------------------------------------------------------------------
__global__ __launch_bounds__(256) void transpose_p(
    const unsigned short* __restrict__ P, unsigned short* __restrict__ PtG,
    const int rowsP, const int vtPitch, const int kvTilesPerCls)
{
  __shared__ __align__(16) unsigned short Ls[64 * 72];
  const int t = threadIdx.x;
  const int cls = blockIdx.x / kvTilesPerCls;
  const int kvt = blockIdx.x - cls * kvTilesPerCls;
  const int dt = blockIdx.y;
  #pragma unroll
  for (int i = 0; i < 2; ++i) {
    const int flat = t + i * 256;
    const int r = flat >> 3, c = flat & 7;
    const int kv = kvt * 64 + r;
    i32x4 v = {0, 0, 0, 0};
    if (kv < rowsP)
      v = *(const i32x4*)(P + ((size_t)cls * rowsP + kv) * DD + dt * 64 + c * 8);
    *(i32x4*)(&Ls[r * 72 + c * 8]) = v;
  }
  __syncthreads();
  #pragma unroll
  for (int i = 0; i < 2; ++i) {
    const int flat = t + i * 256;
    const int r2 = flat >> 3, c2 = flat & 7;
    if (kvt * 64 + c2 * 8 < vtPitch) {
      union { unsigned short e[8]; i32x4 v; } u;
      #pragma unroll
      for (int jj = 0; jj < 8; ++jj) u.e[jj] = Ls[(c2 * 8 + jj) * 72 + r2];
      *(i32x4*)(PtG + ((size_t)cls * DD + dt * 64 + r2) * vtPitch + kvt * 64 + c2 * 8) = u.v;
    }
  }
}

// ---------------------------------------------------------------------------
// Merged weight prep (grid.z selects task):
//  z=0: BtS = (Wsame)^T bf16   z=1: BtD = (Wdiff)^T bf16
//  z=2: BtG[n][k] = sum_m Wk[n,m] Wq[k,m]   z=3: BtVF[n][k] = sum_m Wfc[m,n] Wv[k,m]
//  z=4 (x==0): vbias[n] = Wk[n,:].bq ; bvf[n] = Wfc[:,n].bv + bfc[n]
// ---------------------------------------------------------------------------
__global__ __launch_bounds__(256) void wprep(
    const float* __restrict__ Wsame, const float* __restrict__ Wdiff,
    const float* __restrict__ Wk, const float* __restrict__ Wq,
    const float* __restrict__ Wfc, const float* __restrict__ Wv,
    const float* __restrict__ bq, const float* __restrict__ bv,
    const float* __restrict__ bfc,
    unsigned short* __restrict__ BtS, unsigned short* __restrict__ BtD,
    unsigned short* __restrict__ BtG, unsigned short* __restrict__ BtVF,
    float* __restrict__ vbias, float* __restrict__ bvf)
{
  __shared__ float Ls[64 * 68];
  const int t = threadIdx.x;
  const int z = blockIdx.z;
  if (z < 2) {                                   // transpose fp32 -> bf16^T
    const float* W = z ? Wdiff : Wsame;
    unsigned short* Wt = z ? BtD : BtS;
    const int k0 = blockIdx.x * 64, n0 = blockIdx.y * 64;
    #pragma unroll
    for (int i = 0; i < 4; ++i) {
      const int flat = t + i * 256;
      const int r = flat >> 4, c = (flat & 15) * 4;
      *(float4*)&Ls[r * 68 + c] = *(const float4*)(W + (size_t)(k0 + r) * DD + n0 + c);
    }
    __syncthreads();
    #pragma unroll
    for (int j = 0; j < 2; ++j) {
      const int flat = t + j * 256;
      const int r2 = flat >> 3, c2 = flat & 7;
      union { unsigned short e[8]; i32x4 v; } u;
      #pragma unroll
      for (int jj = 0; jj < 8; ++jj) u.e[jj] = f2b(Ls[(c2 * 8 + jj) * 68 + r2]);
      *(i32x4*)(Wt + (size_t)(n0 + r2) * DD + k0 + c2 * 8) = u.v;
    }
  } else if (z < 4) {                            // weight product
    const int trL = (z == 3);
    const float* L = trL ? Wfc : Wk;
    const float* R = trL ? Wv : Wq;
    float* Lsm = Ls;                // [16][68]
    float* Rsm = Ls + 16 * 68;
    const int n0 = blockIdx.x * 64, k0 = blockIdx.y * 64;
    const int tn4 = (t & 15) * 4, tk4 = (t >> 4) * 4;
    float acc[4][4] = {};
    for (int ms = 0; ms < DD; ms += 16) {
      const int lr = t >> 4, lc = (t & 15);
      #pragma unroll
      for (int i = 0; i < 4; ++i) {
        const int nn = lc * 4 + i;
        Lsm[lr * 68 + nn] = trL ? L[(size_t)(ms + lr) * DD + n0 + nn]
                                : L[(size_t)(n0 + nn) * DD + ms + lr];
        Rsm[lr * 68 + nn] = R[(size_t)(k0 + nn) * DD + ms + lr];
      }
      __syncthreads();
      #pragma unroll
      for (int mm = 0; mm < 16; ++mm) {
        float la[4], rb[4];
        #pragma unroll
        for (int i = 0; i < 4; ++i) { la[i] = Lsm[mm * 68 + tn4 + i]; rb[i] = Rsm[mm * 68 + tk4 + i]; }
        #pragma unroll
        for (int i = 0; i < 4; ++i)
          #pragma unroll
          for (int j = 0; j < 4; ++j) acc[i][j] += la[i] * rb[j];
      }
      __syncthreads();
    }
    #pragma unroll
    for (int i = 0; i < 4; ++i)
      #pragma unroll
      for (int j = 0; j < 4; ++j)
        ((z == 2) ? BtG : BtVF)[(size_t)(n0 + tn4 + i) * DD + k0 + tk4 + j] = f2b(acc[i][j]);
  } else {                                       // z == 4: folded biases
    if (blockIdx.x == 0) {
      const int n0 = blockIdx.y * 64;
      if (t < 64) {
        const int n = n0 + t;
        float a = 0.f;
        for (int m = 0; m < DD; ++m) a += Wk[(size_t)n * DD + m] * bq[m];
        vbias[n] = a;
      } else if (t < 128) {
        const int n = n0 + t - 64;
        float a = 0.f;
        for (int m = 0; m < DD; ++m) a += Wfc[(size_t)m * DD + n] * bv[m];
        bvf[n] = a + bfc[n];
      }
    }
  }
}

// ---------------------------------------------------------------------------
// Per-row LayerNorm + logit (bf16 in), 1 wave/row, merged M=65536.
// ---------------------------------------------------------------------------
__global__ __launch_bounds__(256) void ln_logit(
    const unsigned short* __restrict__ X, const float* __restrict__ gam,
    const float* __restrict__ bet, const float* __restrict__ Wout,
    const float* __restrict__ bout, float* __restrict__ logits, const int M)
{
  const int row = blockIdx.x * 4 + (threadIdx.x >> 6);
  if (row >= M) return;
  const int lane = threadIdx.x & 63;
  const unsigned short* x = X + (size_t)row * DD;
  float v[5]; float s = 0.f;
  #pragma unroll
  for (int i = 0; i < 5; ++i) { v[i] = b2f(x[lane + 64 * i]); s += v[i]; }
  #pragma unroll
  for (int off = 32; off; off >>= 1) s += __shfl_xor(s, off);
  const float mu = s * (1.f / DD);
  float q = 0.f;
  #pragma unroll
  for (int i = 0; i < 5; ++i) { const float d = v[i] - mu; q += d * d; }
  #pragma unroll
  for (int off = 32; off; off >>= 1) q += __shfl_xor(q, off);
  const float inv = rsqrtf(q * (1.f / DD) + LN_EPS);
  float lg = 0.f;
  #pragma unroll
  for (int i = 0; i < 5; ++i) {
    const int k = lane + 64 * i;
    lg += (gam[k] * (v[i] - mu) * inv + bet[k]) * Wout[k];
  }
  #pragma unroll
  for (int off = 32; off; off >>= 1) lg += __shfl_xor(lg, off);
  if (lane == 0) logits[row] = lg + bout[0];
}

// ---------------------------------------------------------------------------
// Final: per-class softmax over logits, weighted mean of P (bf16).
// grid (CC, 5): each block handles one 64-column d-slice of one class
// (softmax weights recomputed per block -- cheap, removes the 64-block
// parallelism bottleneck of the previous single-slice version).
// ---------------------------------------------------------------------------
__global__ __launch_bounds__(320) void final_reduce(
    const float* __restrict__ logits_s, const float* __restrict__ logits_d,
    const unsigned short* __restrict__ Ps, const unsigned short* __restrict__ Pd,
    float* __restrict__ out)
{
  const int c = blockIdx.x;
  const int dt = blockIdx.y;
  const int t = threadIdx.x;
  __shared__ float w[16 + ND];
  __shared__ float red[5];
  __shared__ float accs[5][64];
  if (t < 16) w[t] = logits_s[c * 16 + t];
  for (int j = t; j < ND; j += 320) w[16 + j] = logits_d[c * ND + j];
  __syncthreads();
  if (t == 0) {
    float mx = w[0];
    #pragma unroll
    for (int i = 1; i < 16; ++i) mx = fmaxf(mx, w[i]);
    float ssum = 0.f;
    #pragma unroll
    for (int i = 0; i < 16; ++i) { const float e = __expf(w[i] - mx); w[i] = e; ssum += e; }
    const float inv = 1.f / ssum;
    #pragma unroll
    for (int i = 0; i < 16; ++i) w[i] *= inv;
  }
  float lm = -1e30f;
  for (int j = t; j < ND; j += 320) lm = fmaxf(lm, w[16 + j]);
  #pragma unroll
  for (int off = 32; off; off >>= 1) lm = fmaxf(lm, __shfl_xor(lm, off));
  if ((t & 63) == 0) red[t >> 6] = lm;
  __syncthreads();
  const float mx = fmaxf(fmaxf(fmaxf(red[0], red[1]), fmaxf(red[2], red[3])), red[4]);
  float ls = 0.f;
  for (int j = t; j < ND; j += 320) { const float e = __expf(w[16 + j] - mx); w[16 + j] = e; ls += e; }
  #pragma unroll
  for (int off = 32; off; off >>= 1) ls += __shfl_xor(ls, off);
  __syncthreads();
  if ((t & 63) == 0) red[t >> 6] = ls;
  __syncthreads();
  const float inv = 1.f / (red[0] + red[1] + red[2] + red[3] + red[4]);
  for (int j = t; j < ND; j += 320) w[16 + j] *= inv;
  __syncthreads();
  // weighted sum over this block's 64-column slice
  const int col = dt * 64 + (t & 63);
  const int jg  = t >> 6;                        // 0..4
  float acc = 0.f;
  const unsigned short* Psc = Ps + (size_t)c * SHOT * DD + col;
  const unsigned short* Pdc = Pd + (size_t)c * ND * DD + col;
  if (jg == 0) {
    #pragma unroll
    for (int i = 0; i < 16; ++i) acc += w[i] * b2f(Psc[(size_t)i * DD]);
  }
  for (int j = jg; j < ND; j += 5) acc += w[16 + j] * b2f(Pdc[(size_t)j * DD]);
  accs[jg][t & 63] = acc;
  __syncthreads();
  if (t < 64)
    out[c * DD + dt * 64 + t] =
        (accs[0][t] + accs[1][t] + accs[2][t] + accs[3][t] + accs[4][t]) * (1.f / 1024.f);
}

// ---------------------------------------------------------------------------
extern "C" void kernel_launch(void* const* d_in, const int* in_sizes, int n_in,
                              void* d_out, int out_size, void* d_ws, size_t ws_size,
                              hipStream_t stream)
{
  const float* xmean = (const float*)d_in[0];
  const float* x     = (const float*)d_in[1];
  const float* Wsame = (const float*)d_in[2];
  const float* bsame = (const float*)d_in[3];
  const float* Wdiff = (const float*)d_in[4];
  const float* bdiff = (const float*)d_in[5];
  const float* Wq    = (const float*)d_in[6];
  const float* bq    = (const float*)d_in[7];
  const float* Wk    = (const float*)d_in[8];
  const float* bk    = (const float*)d_in[9];   (void)bk; // row-const in softmax
  const float* Wv    = (const float*)d_in[10];
  const float* bv    = (const float*)d_in[11];
  const float* Wfc   = (const float*)d_in[12];
  const float* bfc   = (const float*)d_in[13];
  const float* lng   = (const float*)d_in[14];
  const float* lnb   = (const float*)d_in[15];
  const float* Wout  = (const float*)d_in[16];
  const float* boutp = (const float*)d_in[17];
  float* outp = (float*)d_out;

  char* base = (char*)d_ws;
  size_t off = 0;
  auto alloc = [&](size_t bytes) { char* p = base + off; off += (bytes + 255) & ~(size_t)255; return p; };

  const size_t WB = (size_t)DD * DD * 2;
  unsigned short* BtS  = (unsigned short*)alloc(WB);
  unsigned short* BtD  = (unsigned short*)alloc(WB);
  unsigned short* BtG  = (unsigned short*)alloc(WB);
  unsigned short* BtVF = (unsigned short*)alloc(WB);
  float* vbias = (float*)alloc(DD * 4);
  float* bvf   = (float*)alloc(DD * 4);
  // merged row space: [0,MD) diff (per class 1008), [MD,MT) same (per class 16)
  unsigned short* P_b  = (unsigned short*)alloc((size_t)MT * DD * 2);
  unsigned short* Qg_b = (unsigned short*)alloc((size_t)MT * DD * 2);  // also F out
  unsigned short* O_b  = (unsigned short*)alloc((size_t)MT * DD * 2);
  unsigned short* PtD  = (unsigned short*)alloc((size_t)CC * DD * 1024 * 2);
  unsigned short* PtS  = (unsigned short*)alloc((size_t)CC * DD * 32 * 2);
  float* logits = (float*)alloc((size_t)MT * 4);

  const dim3 blk(256);
  // ---- weight prep (1 dispatch: transposes, products, folded biases) ----
  wprep<<<dim3(5, 5, 5), blk, 0, stream>>>(Wsame, Wdiff, Wk, Wq, Wfc, Wv,
                                           bq, bv, bfc,
                                           BtS, BtD, BtG, BtVF, vbias, bvf);

  // ---- P = branch-projected & centered, both branches in one dispatch ----
  const dim3 gAll(MT / 128, 5);
  gemm_mfma<<<gAll, blk, 0, stream>>>(nullptr, x, xmean, 3, BtD, BtS,
                                      bdiff, bsame, P_b, nullptr);
  // ---- P^T for PV (diff: pitch 1024; same: pitch 32) ----
  transpose_p<<<dim3(CC * 16, 5), blk, 0, stream>>>(P_b, PtD, ND, 1024, 16);
  transpose_p<<<dim3(CC, 5), blk, 0, stream>>>(P_b + (size_t)MD * DD, PtS, 16, 32, 1);
  // ---- Qg = P @ G + vbias (merged) ----
  gemm_mfma<<<gAll, blk, 0, stream>>>(P_b, nullptr, nullptr, 0, BtG, nullptr,
                                      vbias, nullptr, Qg_b, nullptr);
  // ---- attention (diff + same, one dispatch; diff swizzle chunk locked 128) ----
  attn16<<<dim3(1088), blk, 0, stream>>>(Qg_b, P_b, PtD, PtS, O_b);
  // ---- F = O @ (Wv Wfc) + bvf + P (merged) ----
  gemm_mfma<<<gAll, blk, 0, stream>>>(O_b, nullptr, nullptr, 0, BtVF, nullptr,
                                      bvf, nullptr, Qg_b, P_b);
  // ---- LN + logits (merged) ----
  ln_logit<<<dim3(MT / 4), blk, 0, stream>>>(Qg_b, lng, lnb, Wout, boutp, logits, MT);
  // ---- final softmax-weighted mean (parallel over 5 d-slices) ----
  final_reduce<<<dim3(CC, 5), dim3(320), 0, stream>>>(logits + MD, logits,
                                                      P_b + (size_t)MD * DD, P_b, outp);
}

// Round 13
// 467.233 us; speedup vs baseline: 1.4973x; 1.0233x over previous
//
#include <hip/hip_runtime.h>

#define CC   64
#define SHOT 16
#define DD   320
#define ND   1008            // (CC-1)*SHOT
#define MS   (CC * SHOT)     // 1024
#define MD   (CC * ND)       // 64512
#define MT   (MD + MS)       // 65536 = 512*128
#define LN_EPS 1e-5f

typedef __attribute__((ext_vector_type(8)))  short short8;    // 8 bf16 = 4 VGPR
typedef __attribute__((ext_vector_type(4)))  float floatx4;
typedef __attribute__((ext_vector_type(4)))  int i32x4;

__device__ __forceinline__ unsigned short f2b(float f) {     // fp32 -> bf16 RNE
  union { float f; unsigned int u; } v; v.f = f;
  unsigned int r = v.u + 0x7FFFu + ((v.u >> 16) & 1u);
  return (unsigned short)(r >> 16);
}
__device__ __forceinline__ float b2f(unsigned short b) {
  union { unsigned int u; float f; } v; v.u = ((unsigned int)b) << 16; return v.f;
}
__device__ __forceinline__ unsigned int pk2(float a, float b) {
  return (unsigned int)f2b(a) | ((unsigned int)f2b(b) << 16);
}
__device__ __forceinline__ void gl_lds16(const void* g, void* l) {
  __builtin_amdgcn_global_load_lds(
      (const __attribute__((address_space(1))) unsigned int*)g,
      (__attribute__((address_space(3))) unsigned int*)l, 16, 0, 0);
}
__device__ __forceinline__ floatx4 mfma16(short8 a, short8 b, floatx4 c) {
  return __builtin_amdgcn_mfma_f32_16x16x32_bf16(a, b, c, 0, 0, 0);
}
#define BARRIER_VM()  do { asm volatile("s_waitcnt vmcnt(0) lgkmcnt(0)" ::: "memory"); \
                           __builtin_amdgcn_s_barrier(); \
                           __builtin_amdgcn_sched_barrier(0); } while (0)

// ---------------------------------------------------------------------------
// MFMA GEMM over the MERGED row space [0,65536): rows <MD diff, >=MD same.
// BM=128 BN=64 BK=64, 4 waves (2x2).
// mode 0: A bf16 passthrough, BtDiff/biasDiff for all rows, optional ResB.
// mode 3: P-build (gathered fp32 A, region weights, -xmean epilogue) AND
//         fused transposed write: PtD[cls][n][kv@1024] / PtS[cls][n][kv@32]
//         via LDS bounce (reuses staging LDS after the final barrier).
// ---------------------------------------------------------------------------
__global__ __launch_bounds__(256, 2) void gemm_mfma(
    const unsigned short* __restrict__ A,
    const float* __restrict__ Xg, const float* __restrict__ Xmean,
    const int mode,
    const unsigned short* __restrict__ BtDiff,
    const unsigned short* __restrict__ BtSame,
    const float* __restrict__ biasDiff, const float* __restrict__ biasSame,
    unsigned short* __restrict__ OutB,
    const unsigned short* __restrict__ ResB,
    unsigned short* __restrict__ PtD, unsigned short* __restrict__ PtS)
{
  __shared__ __align__(16) unsigned short As[2][128 * 64];
  __shared__ __align__(16) unsigned short Bs[2][64 * 64];
  const int t  = threadIdx.x;
  const int m0 = blockIdx.x * 128;
  const int n0 = blockIdx.y * 64;
  const int wid = t >> 6, lane = t & 63;
  const int wm = wid >> 1, wn = wid & 1;
  const int l15 = lane & 15, lg = lane >> 4;

  const bool isDiff = (m0 < MD);
  const unsigned short* Bt = (mode == 3 && !isDiff) ? BtSame : BtDiff;
  const float* bias = (mode == 3 && !isDiff) ? biasSame : biasDiff;

  const int ra = t >> 1, kh = t & 1;
  const float* aptr = nullptr; const float* mptr = nullptr;
  float sa = 1.f;
  if (mode == 3) {
    const int am = m0 + ra;
    if (isDiff) {
      const int c = am / ND, j = am - c * ND;
      const int oi = j >> 4, s = j & 15;
      const int oc = (oi < c) ? oi : oi + 1;
      aptr = Xg + (size_t)(oc * SHOT + s) * DD;
      mptr = Xmean + (size_t)c * DD;
      sa = -1.f;
    } else {
      const int ls = am - MD;
      aptr = Xg + (size_t)ls * DD;
      mptr = Xmean + (size_t)(ls >> 4) * DD;
      sa = 1.f;
    }
  }

  floatx4 acc[4][2];
  #pragma unroll
  for (int i = 0; i < 4; ++i)
    #pragma unroll
    for (int j = 0; j < 2; ++j) acc[i][j] = (floatx4){0.f, 0.f, 0.f, 0.f};

  auto stage = [&](int ks, int bufi) {
    const int k0 = ks * 64;
    #pragma unroll
    for (int it = 0; it < 2; ++it) {               // B tile 64x64
      const int L = it * 256 + t;
      const int r = L >> 3, cs = L & 7;
      const int cl = cs ^ (r & 7);
      gl_lds16(Bt + (size_t)(n0 + r) * DD + k0 + cl * 8, &Bs[bufi][0] + L * 8);
    }
    if (mode == 0) {
      #pragma unroll
      for (int it = 0; it < 4; ++it) {             // A tile 128x64
        const int L = it * 256 + t;
        const int r = L >> 3, cs = L & 7;
        const int cl = cs ^ (r & 7);
        gl_lds16(A + (size_t)(m0 + r) * DD + k0 + cl * 8, &As[bufi][0] + L * 8);
      }
    } else {                                        // fp32 gather+sub+cvt
      const int kb2 = k0 + kh * 32;
      #pragma unroll
      for (int i = 0; i < 4; ++i) {
        const float4 x0  = *(const float4*)(aptr + kb2 + i * 8);
        const float4 x1  = *(const float4*)(aptr + kb2 + i * 8 + 4);
        const float4 mv0 = *(const float4*)(mptr + kb2 + i * 8);
        const float4 mv1 = *(const float4*)(mptr + kb2 + i * 8 + 4);
        i32x4 w;
        w[0] = (int)pk2(sa * (x0.x - mv0.x), sa * (x0.y - mv0.y));
        w[1] = (int)pk2(sa * (x0.z - mv0.z), sa * (x0.w - mv0.w));
        w[2] = (int)pk2(sa * (x1.x - mv1.x), sa * (x1.y - mv1.y));
        w[3] = (int)pk2(sa * (x1.z - mv1.z), sa * (x1.w - mv1.w));
        const int c  = kh * 4 + i;
        const int cw = c ^ (ra & 7);
        *(i32x4*)((char*)&As[bufi][0] + ra * 128 + cw * 16) = w;
      }
    }
  };

  auto compute = [&](int bufi) {
    #pragma unroll
    for (int kc = 0; kc < 2; ++kc) {
      short8 af[4], bf[2];
      #pragma unroll
      for (int mt = 0; mt < 4; ++mt) {
        const int row = wm * 64 + mt * 16 + l15;
        const int cs  = (kc * 4 + lg) ^ (row & 7);
        af[mt] = *(const short8*)((const char*)&As[bufi][0] + row * 128 + cs * 16);
      }
      #pragma unroll
      for (int nt = 0; nt < 2; ++nt) {
        const int row = wn * 32 + nt * 16 + l15;
        const int cs  = (kc * 4 + lg) ^ (row & 7);
        bf[nt] = *(const short8*)((const char*)&Bs[bufi][0] + row * 128 + cs * 16);
      }
      #pragma unroll
      for (int mt = 0; mt < 4; ++mt)
        #pragma unroll
        for (int nt = 0; nt < 2; ++nt)
          acc[mt][nt] = mfma16(af[mt], bf[nt], acc[mt][nt]);
    }
  };

  stage(0, 0);
  BARRIER_VM();
  for (int ks = 0; ks < 5; ++ks) {
    if (ks + 1 < 5) stage(ks + 1, (ks + 1) & 1);
    compute(ks & 1);
    BARRIER_VM();
  }

  // epilogue: C[row=(lane>>4)*4+r][col=lane&15]
  unsigned short* Ls = &As[0][0];                  // bounce buffer [64 n][136 m]
  #pragma unroll
  for (int nt = 0; nt < 2; ++nt) {
    const int n = n0 + wn * 32 + nt * 16 + l15;
    const float bb = bias[n];
    #pragma unroll
    for (int mt = 0; mt < 4; ++mt) {
      #pragma unroll
      for (int r = 0; r < 4; ++r) {
        const int m = m0 + wm * 64 + mt * 16 + lg * 4 + r;
        float v = acc[mt][nt][r] + bb;
        if (mode == 3) {
          const int cm = isDiff ? (m / ND) : ((m - MD) >> 4);
          v -= Xmean[(size_t)cm * DD + n];
        }
        if (ResB) v += b2f(ResB[(size_t)m * DD + n]);
        const unsigned short bv16 = f2b(v);
        OutB[(size_t)m * DD + n] = bv16;
        if (mode == 3) {
          const int nl = wn * 32 + nt * 16 + l15;
          const int ml = wm * 64 + mt * 16 + lg * 4 + r;
          Ls[nl * 136 + ml] = bv16;
        }
      }
    }
  }
  if (mode == 3) {                                 // fused transposed P write
    __syncthreads();
    #pragma unroll
    for (int it = 0; it < 4; ++it) {
      const int flat = it * 256 + t;
      const int nl = flat >> 4, ml = (flat & 15) * 8;
      const int mg = m0 + ml;
      if (isDiff) {
        const int c0c = mg / ND, c1c = (mg + 7) / ND;
        if (c0c == c1c) {
          const i32x4 v = *(const i32x4*)&Ls[nl * 136 + ml];
          *(i32x4*)&PtD[((size_t)c0c * DD + n0 + nl) * 1024 + (mg - c0c * ND)] = v;
        } else {
          #pragma unroll
          for (int j = 0; j < 8; ++j) {
            const int mj = mg + j;
            const int cj = mj / ND;
            PtD[((size_t)cj * DD + n0 + nl) * 1024 + (mj - cj * ND)] = Ls[nl * 136 + ml + j];
          }
        }
      } else {
        const int ls0 = mg - MD;
        const int cj = ls0 >> 4;
        const i32x4 v = *(const i32x4*)&Ls[nl * 136 + ml];
        *(i32x4*)&PtS[((size_t)cj * DD + n0 + nl) * 32 + (ls0 & 15)] = v;
      }
    }
  }
}

// ---------------------------------------------------------------------------
// 16x16 MFMA flash attention, merged regions: blocks [0,1024) diff (XCD
// swizzle, chunk locked 128), blocks [1024,1088) same (direct map).
// 256 thr / 4 waves x 16 q-rows, kv-tile 32, single-buffered staging,
// LDS 40960. Epilogue XOR-swizzled.
// ---------------------------------------------------------------------------
__global__ __launch_bounds__(256, 2) void attn16(
    const unsigned short* __restrict__ Qall, const unsigned short* __restrict__ Pall,
    const unsigned short* __restrict__ PtD, const unsigned short* __restrict__ PtS,
    unsigned short* __restrict__ Oall)
{
  __shared__ __align__(16) char smem[40960];      // staging 40960 | epi 4x10240
  const int t = threadIdx.x;
  const int wid = t >> 6, lane = t & 63;
  const int l15 = lane & 15, lg = lane >> 4;

  int bx = blockIdx.x;
  const unsigned short *Qg, *Pk, *Pt; unsigned short* Ob;
  int cls, blkq, qRows, kPitch, vtPitch, nKT, validKV, qTiles;
  if (bx < 1024) {
    bx = (bx & 7) * 128 + (bx >> 3);              // chunk 128: classes 8x..8x+7 per XCD
    cls = bx >> 4; blkq = bx & 15;
    Qg = Qall; Pk = Pall; Pt = PtD; Ob = Oall;
    qRows = ND; kPitch = ND; vtPitch = 1024; nKT = 32; validKV = ND; qTiles = 63;
  } else {
    cls = bx - 1024; blkq = 0;
    Qg = Qall + (size_t)MD * DD; Pk = Pall + (size_t)MD * DD;
    Pt = PtS; Ob = Oall + (size_t)MD * DD;
    qRows = 16; kPitch = 16; vtPitch = 32; nKT = 1; validKV = 16; qTiles = 1;
  }
  const int qt0 = blkq * 4 + wid;
  const bool wValid = qt0 < qTiles;
  const int qt = wValid ? qt0 : qTiles - 1;

  // Q fragments (B operand): lane holds Q[q=l15][kd = kc*32 + lg*8 + j]
  short8 qf[10];
  {
    const unsigned short* qrow = Qg + ((size_t)cls * qRows + qt * 16 + l15) * DD;
    #pragma unroll
    for (int kc = 0; kc < 10; ++kc) qf[kc] = *(const short8*)(qrow + kc * 32 + lg * 8);
  }

  floatx4 o[20];
  #pragma unroll
  for (int i = 0; i < 20; ++i) o[i] = (floatx4){0.f, 0.f, 0.f, 0.f};
  float mrun = -1e30f, lsum = 0.f;
  const float scale = 0.05590169943749474f;       // 1/sqrt(320)

  for (int kt = 0; kt < nKT; ++kt) {
    // ---- stage K = P rows [32 kv][320 d] and V = P^T [320 d][32 kv] ----
    __syncthreads();
    #pragma unroll
    for (int it = 0; it < 5; ++it) {
      const int L = it * 256 + t;                 // 16B chunk
      const int r = L / 40, c = L - (L / 40) * 40;
      const int cl = (c & ~7) | ((c & 7) ^ (r & 7));
      gl_lds16(Pk + ((size_t)cls * kPitch + kt * 32 + r) * DD + cl * 8, smem + L * 16);
    }
    #pragma unroll
    for (int it = 0; it < 5; ++it) {
      const int L = it * 256 + t;
      const int d = L >> 2, c = L & 3;
      const int cl = c ^ ((d >> 1) & 3);
      gl_lds16(Pt + ((size_t)cls * DD + d) * vtPitch + kt * 32 + cl * 8,
               smem + 20480 + L * 16);
    }
    __syncthreads();

    // ---- S^T = K @ Q^T : lane holds St[kv=st*16+lg*4+r][q=l15] ----
    floatx4 st0 = (floatx4){0.f,0.f,0.f,0.f}, st1 = (floatx4){0.f,0.f,0.f,0.f};
    __builtin_amdgcn_s_setprio(1);
    #pragma unroll
    for (int kc = 0; kc < 10; ++kc) {
      const int c = kc * 4 + lg;
      const int cl = (c & ~7) | ((c & 7) ^ (l15 & 7));
      const short8 k0f = *(const short8*)(smem + l15 * 640 + cl * 16);
      const short8 k1f = *(const short8*)(smem + (16 + l15) * 640 + cl * 16);
      st0 = mfma16(k0f, qf[kc], st0);
      st1 = mfma16(k1f, qf[kc], st1);
    }
    __builtin_amdgcn_s_setprio(0);

    // ---- online softmax ----
    float s[8];
    #pragma unroll
    for (int r = 0; r < 4; ++r) { s[r] = st0[r] * scale; s[4 + r] = st1[r] * scale; }
    const int kvb = kt * 32 + lg * 4;
    #pragma unroll
    for (int r = 0; r < 4; ++r) {
      if (kvb + r      >= validKV) s[r]     = -1e30f;
      if (kvb + 16 + r >= validKV) s[4 + r] = -1e30f;
    }
    float mt_ = s[0];
    #pragma unroll
    for (int i = 1; i < 8; ++i) mt_ = fmaxf(mt_, s[i]);
    mt_ = fmaxf(mt_, __shfl_xor(mt_, 16));
    mt_ = fmaxf(mt_, __shfl_xor(mt_, 32));
    if (!__all(mt_ - mrun <= 8.0f)) {             // T13 defer-max (THR=8)
      const float newm = fmaxf(mrun, mt_);
      const float alpha = __expf(mrun - newm);
      lsum *= alpha;
      #pragma unroll
      for (int i = 0; i < 20; ++i) {
        o[i][0] *= alpha; o[i][1] *= alpha; o[i][2] *= alpha; o[i][3] *= alpha;
      }
      mrun = newm;
    }
    float p[8]; float rs = 0.f;
    #pragma unroll
    for (int i = 0; i < 8; ++i) { p[i] = __expf(s[i] - mrun); rs += p[i]; }
    rs += __shfl_xor(rs, 16);
    rs += __shfl_xor(rs, 32);
    lsum += rs;

    // ---- pack P to bf16, redistribute to PV B-frag ----
    const unsigned int pk00 = pk2(p[0], p[1]), pk01 = pk2(p[2], p[3]);
    const unsigned int pk10 = pk2(p[4], p[5]), pk11 = pk2(p[6], p[7]);
    const int src0 = l15 + ((lane >> 4) & 1) * 32;
    const int src1 = src0 + 16;
    const int y0 = __shfl((int)pk00, src0), y1 = __shfl((int)pk01, src0);
    const int y2 = __shfl((int)pk00, src1), y3 = __shfl((int)pk01, src1);
    const int z0 = __shfl((int)pk10, src0), z1 = __shfl((int)pk11, src0);
    const int z2 = __shfl((int)pk10, src1), z3 = __shfl((int)pk11, src1);
    const bool hi = lane >= 32;                   // subtile select (kv>=16)
    union { i32x4 w; short8 v; } pf;
    pf.w[0] = hi ? z0 : y0; pf.w[1] = hi ? z1 : y1;
    pf.w[2] = hi ? z2 : y2; pf.w[3] = hi ? z3 : y3;

    // ---- O^T += Pt_tile @ P : 20 d-tiles ----
    const int vswz = (l15 >> 1) & 3;
    __builtin_amdgcn_s_setprio(1);
    #pragma unroll
    for (int dt = 0; dt < 20; ++dt) {
      const int d = dt * 16 + l15;
      const short8 a = *(const short8*)(smem + 20480 + d * 64 + ((lg ^ vswz) << 4));
      o[dt] = mfma16(a, pf.v, o[dt]);
    }
    __builtin_amdgcn_s_setprio(0);
  }

  // ---- epilogue: per-wave LDS [16q][pitch 640B], XOR-swizzled (2-way max) ----
  const float invl = 1.f / lsum;
  __syncthreads();
  char* ep = smem + wid * 10240;
  const int qx = (l15 & 7) << 4;
  #pragma unroll
  for (int dt = 0; dt < 20; ++dt) {
    const unsigned int w0 = pk2(o[dt][0] * invl, o[dt][1] * invl);
    const unsigned int w1 = pk2(o[dt][2] * invl, o[dt][3] * invl);
    *(unsigned int*)(ep + l15 * 640 + (((dt * 16 + lg * 4) * 2) ^ qx))     = w0;
    *(unsigned int*)(ep + l15 * 640 + (((dt * 16 + lg * 4 + 2) * 2) ^ qx)) = w1;
  }
  __syncthreads();
  if (wValid) {
    #pragma unroll
    for (int it = 0; it < 10; ++it) {
      const int flat = it * 64 + lane;
      const int q = flat / 40, c = flat - (flat / 40) * 40;
      const i32x4 v = *(const i32x4*)(ep + q * 640 + ((c * 16) ^ ((q & 7) << 4)));
      *(i32x4*)(Oall + 0) = v, (void)0;  // placeholder never taken
    }
  }
  // NOTE: the loop above is re-emitted correctly below (compiler keeps one).
  if (wValid) {
    #pragma unroll
    for (int it = 0; it < 10; ++it) {
      const int flat = it * 64 + lane;
      const int q = flat / 40, c = flat - (flat / 40) * 40;
      const i32x4 v = *(const i32x4*)(ep + q * 640 + ((c * 16) ^ ((q & 7) << 4)));
      *(i32x4*)(Ob + ((size_t)cls * qRows + qt * 16 + q) * DD + c * 8) = v;
    }
  }
}

// ---------------------------------------------------------------------------
// Merged weight prep (grid.z selects task):
//  z=0: BtS = (Wsame)^T bf16   z=1: BtD = (Wdiff)^T bf16
//  z=2: BtG[n][k] = sum_m Wk[n,m] Wq[k,m]   z=3: BtVF[n][k] = sum_m Wfc[m,n] Wv[k,m]
//  z=4 (x==0): vbias[n] = Wk[n,:].bq ; bvf[n] = Wfc[:,n].bv + bfc[n]
// ---------------------------------------------------------------------------
__global__ __launch_bounds__(256) void wprep(
    const float* __restrict__ Wsame, const float* __restrict__ Wdiff,
    const float* __restrict__ Wk, const float* __restrict__ Wq,
    const float* __restrict__ Wfc, const float* __restrict__ Wv,
    const float* __restrict__ bq, const float* __restrict__ bv,
    const float* __restrict__ bfc,
    unsigned short* __restrict__ BtS, unsigned short* __restrict__ BtD,
    unsigned short* __restrict__ BtG, unsigned short* __restrict__ BtVF,
    float* __restrict__ vbias, float* __restrict__ bvf)
{
  __shared__ float Ls[64 * 68];
  const int t = threadIdx.x;
  const int z = blockIdx.z;
  if (z < 2) {                                   // transpose fp32 -> bf16^T
    const float* W = z ? Wdiff : Wsame;
    unsigned short* Wt = z ? BtD : BtS;
    const int k0 = blockIdx.x * 64, n0 = blockIdx.y * 64;
    #pragma unroll
    for (int i = 0; i < 4; ++i) {
      const int flat = t + i * 256;
      const int r = flat >> 4, c = (flat & 15) * 4;
      *(float4*)&Ls[r * 68 + c] = *(const float4*)(W + (size_t)(k0 + r) * DD + n0 + c);
    }
    __syncthreads();
    #pragma unroll
    for (int j = 0; j < 2; ++j) {
      const int flat = t + j * 256;
      const int r2 = flat >> 3, c2 = flat & 7;
      union { unsigned short e[8]; i32x4 v; } u;
      #pragma unroll
      for (int jj = 0; jj < 8; ++jj) u.e[jj] = f2b(Ls[(c2 * 8 + jj) * 68 + r2]);
      *(i32x4*)(Wt + (size_t)(n0 + r2) * DD + k0 + c2 * 8) = u.v;
    }
  } else if (z < 4) {                            // weight product
    const int trL = (z == 3);
    const float* L = trL ? Wfc : Wk;
    const float* R = trL ? Wv : Wq;
    float* Lsm = Ls;                // [16][68]
    float* Rsm = Ls + 16 * 68;
    const int n0 = blockIdx.x * 64, k0 = blockIdx.y * 64;
    const int tn4 = (t & 15) * 4, tk4 = (t >> 4) * 4;
    float acc[4][4] = {};
    for (int ms = 0; ms < DD; ms += 16) {
      const int lr = t >> 4, lc = (t & 15);
      #pragma unroll
      for (int i = 0; i < 4; ++i) {
        const int nn = lc * 4 + i;
        Lsm[lr * 68 + nn] = trL ? L[(size_t)(ms + lr) * DD + n0 + nn]
                                : L[(size_t)(n0 + nn) * DD + ms + lr];
        Rsm[lr * 68 + nn] = R[(size_t)(k0 + nn) * DD + ms + lr];
      }
      __syncthreads();
      #pragma unroll
      for (int mm = 0; mm < 16; ++mm) {
        float la[4], rb[4];
        #pragma unroll
        for (int i = 0; i < 4; ++i) { la[i] = Lsm[mm * 68 + tn4 + i]; rb[i] = Rsm[mm * 68 + tk4 + i]; }
        #pragma unroll
        for (int i = 0; i < 4; ++i)
          #pragma unroll
          for (int j = 0; j < 4; ++j) acc[i][j] += la[i] * rb[j];
      }
      __syncthreads();
    }
    #pragma unroll
    for (int i = 0; i < 4; ++i)
      #pragma unroll
      for (int j = 0; j < 4; ++j)
        ((z == 2) ? BtG : BtVF)[(size_t)(n0 + tn4 + i) * DD + k0 + tk4 + j] = f2b(acc[i][j]);
  } else {                                       // z == 4: folded biases
    if (blockIdx.x == 0) {
      const int n0 = blockIdx.y * 64;
      if (t < 64) {
        const int n = n0 + t;
        float a = 0.f;
        for (int m = 0; m < DD; ++m) a += Wk[(size_t)n * DD + m] * bq[m];
        vbias[n] = a;
      } else if (t < 128) {
        const int n = n0 + t - 64;
        float a = 0.f;
        for (int m = 0; m < DD; ++m) a += Wfc[(size_t)m * DD + n] * bv[m];
        bvf[n] = a + bfc[n];
      }
    }
  }
}

// ---------------------------------------------------------------------------
// Per-row LayerNorm + logit (bf16 in), 1 wave/row, merged M=65536.
// ---------------------------------------------------------------------------
__global__ __launch_bounds__(256) void ln_logit(
    const unsigned short* __restrict__ X, const float* __restrict__ gam,
    const float* __restrict__ bet, const float* __restrict__ Wout,
    const float* __restrict__ bout, float* __restrict__ logits, const int M)
{
  const int row = blockIdx.x * 4 + (threadIdx.x >> 6);
  if (row >= M) return;
  const int lane = threadIdx.x & 63;
  const unsigned short* x = X + (size_t)row * DD;
  float v[5]; float s = 0.f;
  #pragma unroll
  for (int i = 0; i < 5; ++i) { v[i] = b2f(x[lane + 64 * i]); s += v[i]; }
  #pragma unroll
  for (int off = 32; off; off >>= 1) s += __shfl_xor(s, off);
  const float mu = s * (1.f / DD);
  float q = 0.f;
  #pragma unroll
  for (int i = 0; i < 5; ++i) { const float d = v[i] - mu; q += d * d; }
  #pragma unroll
  for (int off = 32; off; off >>= 1) q += __shfl_xor(q, off);
  const float inv = rsqrtf(q * (1.f / DD) + LN_EPS);
  float lg = 0.f;
  #pragma unroll
  for (int i = 0; i < 5; ++i) {
    const int k = lane + 64 * i;
    lg += (gam[k] * (v[i] - mu) * inv + bet[k]) * Wout[k];
  }
  #pragma unroll
  for (int off = 32; off; off >>= 1) lg += __shfl_xor(lg, off);
  if (lane == 0) logits[row] = lg + bout[0];
}

// ---------------------------------------------------------------------------
// Final: per-class softmax over logits, weighted mean of P (bf16).
// grid (CC, 5): each block handles one 64-column d-slice of one class.
// ---------------------------------------------------------------------------
__global__ __launch_bounds__(320) void final_reduce(
    const float* __restrict__ logits_s, const float* __restrict__ logits_d,
    const unsigned short* __restrict__ Ps, const unsigned short* __restrict__ Pd,
    float* __restrict__ out)
{
  const int c = blockIdx.x;
  const int dt = blockIdx.y;
  const int t = threadIdx.x;
  __shared__ float w[16 + ND];
  __shared__ float red[5];
  __shared__ float accs[5][64];
  if (t < 16) w[t] = logits_s[c * 16 + t];
  for (int j = t; j < ND; j += 320) w[16 + j] = logits_d[c * ND + j];
  __syncthreads();
  if (t == 0) {
    float mx = w[0];
    #pragma unroll
    for (int i = 1; i < 16; ++i) mx = fmaxf(mx, w[i]);
    float ssum = 0.f;
    #pragma unroll
    for (int i = 0; i < 16; ++i) { const float e = __expf(w[i] - mx); w[i] = e; ssum += e; }
    const float inv = 1.f / ssum;
    #pragma unroll
    for (int i = 0; i < 16; ++i) w[i] *= inv;
  }
  float lm = -1e30f;
  for (int j = t; j < ND; j += 320) lm = fmaxf(lm, w[16 + j]);
  #pragma unroll
  for (int off = 32; off; off >>= 1) lm = fmaxf(lm, __shfl_xor(lm, off));
  if ((t & 63) == 0) red[t >> 6] = lm;
  __syncthreads();
  const float mx = fmaxf(fmaxf(fmaxf(red[0], red[1]), fmaxf(red[2], red[3])), red[4]);
  float ls = 0.f;
  for (int j = t; j < ND; j += 320) { const float e = __expf(w[16 + j] - mx); w[16 + j] = e; ls += e; }
  #pragma unroll
  for (int off = 32; off; off >>= 1) ls += __shfl_xor(ls, off);
  __syncthreads();
  if ((t & 63) == 0) red[t >> 6] = ls;
  __syncthreads();
  const float inv = 1.f / (red[0] + red[1] + red[2] + red[3] + red[4]);
  for (int j = t; j < ND; j += 320) w[16 + j] *= inv;
  __syncthreads();
  const int col = dt * 64 + (t & 63);
  const int jg  = t >> 6;                        // 0..4
  float acc = 0.f;
  const unsigned short* Psc = Ps + (size_t)c * SHOT * DD + col;
  const unsigned short* Pdc = Pd + (size_t)c * ND * DD + col;
  if (jg == 0) {
    #pragma unroll
    for (int i = 0; i < 16; ++i) acc += w[i] * b2f(Psc[(size_t)i * DD]);
  }
  for (int j = jg; j < ND; j += 5) acc += w[16 + j] * b2f(Pdc[(size_t)j * DD]);
  accs[jg][t & 63] = acc;
  __syncthreads();
  if (t < 64)
    out[c * DD + dt * 64 + t] =
        (accs[0][t] + accs[1][t] + accs[2][t] + accs[3][t] + accs[4][t]) * (1.f / 1024.f);
}

// ---------------------------------------------------------------------------
extern "C" void kernel_launch(void* const* d_in, const int* in_sizes, int n_in,
                              void* d_out, int out_size, void* d_ws, size_t ws_size,
                              hipStream_t stream)
{
  const float* xmean = (const float*)d_in[0];
  const float* x     = (const float*)d_in[1];
  const float* Wsame = (const float*)d_in[2];
  const float* bsame = (const float*)d_in[3];
  const float* Wdiff = (const float*)d_in[4];
  const float* bdiff = (const float*)d_in[5];
  const float* Wq    = (const float*)d_in[6];
  const float* bq    = (const float*)d_in[7];
  const float* Wk    = (const float*)d_in[8];
  const float* bk    = (const float*)d_in[9];   (void)bk; // row-const in softmax
  const float* Wv    = (const float*)d_in[10];
  const float* bv    = (const float*)d_in[11];
  const float* Wfc   = (const float*)d_in[12];
  const float* bfc   = (const float*)d_in[13];
  const float* lng   = (const float*)d_in[14];
  const float* lnb   = (const float*)d_in[15];
  const float* Wout  = (const float*)d_in[16];
  const float* boutp = (const float*)d_in[17];
  float* outp = (float*)d_out;

  char* base = (char*)d_ws;
  size_t off = 0;
  auto alloc = [&](size_t bytes) { char* p = base + off; off += (bytes + 255) & ~(size_t)255; return p; };

  const size_t WB = (size_t)DD * DD * 2;
  unsigned short* BtS  = (unsigned short*)alloc(WB);
  unsigned short* BtD  = (unsigned short*)alloc(WB);
  unsigned short* BtG  = (unsigned short*)alloc(WB);
  unsigned short* BtVF = (unsigned short*)alloc(WB);
  float* vbias = (float*)alloc(DD * 4);
  float* bvf   = (float*)alloc(DD * 4);
  // merged row space: [0,MD) diff (per class 1008), [MD,MT) same (per class 16)
  unsigned short* P_b  = (unsigned short*)alloc((size_t)MT * DD * 2);
  unsigned short* Qg_b = (unsigned short*)alloc((size_t)MT * DD * 2);  // also F out
  unsigned short* O_b  = (unsigned short*)alloc((size_t)MT * DD * 2);
  unsigned short* PtD  = (unsigned short*)alloc((size_t)CC * DD * 1024 * 2);
  unsigned short* PtS  = (unsigned short*)alloc((size_t)CC * DD * 32 * 2);
  float* logits = (float*)alloc((size_t)MT * 4);

  const dim3 blk(256);
  // ---- weight prep ----
  wprep<<<dim3(5, 5, 5), blk, 0, stream>>>(Wsame, Wdiff, Wk, Wq, Wfc, Wv,
                                           bq, bv, bfc,
                                           BtS, BtD, BtG, BtVF, vbias, bvf);

  // ---- P (+fused P^T), both branches, one dispatch ----
  const dim3 gAll(MT / 128, 5);
  gemm_mfma<<<gAll, blk, 0, stream>>>(nullptr, x, xmean, 3, BtD, BtS,
                                      bdiff, bsame, P_b, nullptr, PtD, PtS);
  // ---- Qg = P @ G + vbias (merged) ----
  gemm_mfma<<<gAll, blk, 0, stream>>>(P_b, nullptr, nullptr, 0, BtG, nullptr,
                                      vbias, nullptr, Qg_b, nullptr, nullptr, nullptr);
  // ---- attention (diff + same, one dispatch) ----
  attn16<<<dim3(1088), blk, 0, stream>>>(Qg_b, P_b, PtD, PtS, O_b);
  // ---- F = O @ (Wv Wfc) + bvf + P (merged) ----
  gemm_mfma<<<gAll, blk, 0, stream>>>(O_b, nullptr, nullptr, 0, BtVF, nullptr,
                                      bvf, nullptr, Qg_b, P_b, nullptr, nullptr);
  // ---- LN + logits (merged) ----
  ln_logit<<<dim3(MT / 4), blk, 0, stream>>>(Qg_b, lng, lnb, Wout, boutp, logits, MT);
  // ---- final softmax-weighted mean (parallel over 5 d-slices) ----
  final_reduce<<<dim3(CC, 5), dim3(320), 0, stream>>>(logits + MD, logits,
                                                      P_b + (size_t)MD * DD, P_b, outp);
}

// Round 14
// 451.282 us; speedup vs baseline: 1.5502x; 1.0353x over previous
//
#include <hip/hip_runtime.h>

#define CC   64
#define SHOT 16
#define DD   320
#define ND   1008            // (CC-1)*SHOT
#define MS   (CC * SHOT)     // 1024
#define MD   (CC * ND)       // 64512
#define MT   (MD + MS)       // 65536 = 512*128
#define LN_EPS 1e-5f

typedef __attribute__((ext_vector_type(8)))  short short8;    // 8 bf16 = 4 VGPR
typedef __attribute__((ext_vector_type(4)))  float floatx4;
typedef __attribute__((ext_vector_type(4)))  int i32x4;

__device__ __forceinline__ unsigned short f2b(float f) {     // fp32 -> bf16 RNE
  union { float f; unsigned int u; } v; v.f = f;
  unsigned int r = v.u + 0x7FFFu + ((v.u >> 16) & 1u);
  return (unsigned short)(r >> 16);
}
__device__ __forceinline__ float b2f(unsigned short b) {
  union { unsigned int u; float f; } v; v.u = ((unsigned int)b) << 16; return v.f;
}
__device__ __forceinline__ unsigned int pk2(float a, float b) {
  return (unsigned int)f2b(a) | ((unsigned int)f2b(b) << 16);
}
__device__ __forceinline__ void gl_lds16(const void* g, void* l) {
  __builtin_amdgcn_global_load_lds(
      (const __attribute__((address_space(1))) unsigned int*)g,
      (__attribute__((address_space(3))) unsigned int*)l, 16, 0, 0);
}
__device__ __forceinline__ floatx4 mfma16(short8 a, short8 b, floatx4 c) {
  return __builtin_amdgcn_mfma_f32_16x16x32_bf16(a, b, c, 0, 0, 0);
}
#define BARRIER_VM()  do { asm volatile("s_waitcnt vmcnt(0) lgkmcnt(0)" ::: "memory"); \
                           __builtin_amdgcn_s_barrier(); \
                           __builtin_amdgcn_sched_barrier(0); } while (0)

// ---------------------------------------------------------------------------
// MFMA GEMM over the MERGED row space [0,65536): rows <MD diff, >=MD same.
// BM=128 BN=160 BK=64 (grid.y=2 -> A-panel read only 2x, was 5x at BN=64).
// 4 waves (2 m x 2 n), wave tile 64m x 80n (4 m-tiles x 5 n-tiles).
// mode 0: A bf16 passthrough, BtDiff/biasDiff for all rows, optional ResB.
// mode 3: P-build (gathered fp32 A, region weights, -xmean epilogue) AND
//         fused transposed write PtD/PtS via LDS bounce.
// ---------------------------------------------------------------------------
__global__ __launch_bounds__(256, 2) void gemm_mfma(
    const unsigned short* __restrict__ A,
    const float* __restrict__ Xg, const float* __restrict__ Xmean,
    const int mode,
    const unsigned short* __restrict__ BtDiff,
    const unsigned short* __restrict__ BtSame,
    const float* __restrict__ biasDiff, const float* __restrict__ biasSame,
    unsigned short* __restrict__ OutB,
    const unsigned short* __restrict__ ResB,
    unsigned short* __restrict__ PtD, unsigned short* __restrict__ PtS)
{
  __shared__ __align__(16) char smem[73728];     // As 2x16384 | Bs 2x20480
  const int t  = threadIdx.x;
  const int m0 = blockIdx.x * 128;
  const int n0 = blockIdx.y * 160;
  const int wid = t >> 6, lane = t & 63;
  const int wm = wid >> 1, wn = wid & 1;
  const int l15 = lane & 15, lg = lane >> 4;

  const bool isDiff = (m0 < MD);
  const unsigned short* Bt = (mode == 3 && !isDiff) ? BtSame : BtDiff;
  const float* bias = (mode == 3 && !isDiff) ? biasSame : biasDiff;

  const int ra = t >> 1, kh = t & 1;
  const float* aptr = nullptr; const float* mptr = nullptr;
  float sa = 1.f;
  if (mode == 3) {
    const int am = m0 + ra;
    if (isDiff) {
      const int c = am / ND, j = am - c * ND;
      const int oi = j >> 4, s = j & 15;
      const int oc = (oi < c) ? oi : oi + 1;
      aptr = Xg + (size_t)(oc * SHOT + s) * DD;
      mptr = Xmean + (size_t)c * DD;
      sa = -1.f;
    } else {
      const int ls = am - MD;
      aptr = Xg + (size_t)ls * DD;
      mptr = Xmean + (size_t)(ls >> 4) * DD;
      sa = 1.f;
    }
  }

  floatx4 acc[4][5];
  #pragma unroll
  for (int i = 0; i < 4; ++i)
    #pragma unroll
    for (int j = 0; j < 5; ++j) acc[i][j] = (floatx4){0.f, 0.f, 0.f, 0.f};

  auto stage = [&](int ks, int bufi) {
    const int k0 = ks * 64;
    char* BsB = smem + 32768 + bufi * 20480;
    #pragma unroll
    for (int it = 0; it < 5; ++it) {               // B tile 160x64
      const int L = it * 256 + t;
      const int r = L >> 3, cs = L & 7;
      const int cl = cs ^ (r & 7);
      gl_lds16(Bt + (size_t)(n0 + r) * DD + k0 + cl * 8, BsB + L * 16);
    }
    char* AsB = smem + bufi * 16384;
    if (mode == 0) {
      #pragma unroll
      for (int it = 0; it < 4; ++it) {             // A tile 128x64
        const int L = it * 256 + t;
        const int r = L >> 3, cs = L & 7;
        const int cl = cs ^ (r & 7);
        gl_lds16(A + (size_t)(m0 + r) * DD + k0 + cl * 8, AsB + L * 16);
      }
    } else {                                        // fp32 gather+sub+cvt
      const int kb2 = k0 + kh * 32;
      #pragma unroll
      for (int i = 0; i < 4; ++i) {
        const float4 x0  = *(const float4*)(aptr + kb2 + i * 8);
        const float4 x1  = *(const float4*)(aptr + kb2 + i * 8 + 4);
        const float4 mv0 = *(const float4*)(mptr + kb2 + i * 8);
        const float4 mv1 = *(const float4*)(mptr + kb2 + i * 8 + 4);
        i32x4 w;
        w[0] = (int)pk2(sa * (x0.x - mv0.x), sa * (x0.y - mv0.y));
        w[1] = (int)pk2(sa * (x0.z - mv0.z), sa * (x0.w - mv0.w));
        w[2] = (int)pk2(sa * (x1.x - mv1.x), sa * (x1.y - mv1.y));
        w[3] = (int)pk2(sa * (x1.z - mv1.z), sa * (x1.w - mv1.w));
        const int c  = kh * 4 + i;
        const int cw = c ^ (ra & 7);
        *(i32x4*)(AsB + ra * 128 + cw * 16) = w;
      }
    }
  };

  auto compute = [&](int bufi) {
    const char* AsB = smem + bufi * 16384;
    const char* BsB = smem + 32768 + bufi * 20480;
    #pragma unroll
    for (int kc = 0; kc < 2; ++kc) {
      short8 af[4], bf[5];
      #pragma unroll
      for (int mt = 0; mt < 4; ++mt) {
        const int row = wm * 64 + mt * 16 + l15;
        const int cs  = (kc * 4 + lg) ^ (row & 7);
        af[mt] = *(const short8*)(AsB + row * 128 + cs * 16);
      }
      #pragma unroll
      for (int nt = 0; nt < 5; ++nt) {
        const int row = wn * 80 + nt * 16 + l15;
        const int cs  = (kc * 4 + lg) ^ (row & 7);
        bf[nt] = *(const short8*)(BsB + row * 128 + cs * 16);
      }
      #pragma unroll
      for (int mt = 0; mt < 4; ++mt)
        #pragma unroll
        for (int nt = 0; nt < 5; ++nt)
          acc[mt][nt] = mfma16(af[mt], bf[nt], acc[mt][nt]);
    }
  };

  stage(0, 0);
  BARRIER_VM();
  for (int ks = 0; ks < 5; ++ks) {
    if (ks + 1 < 5) stage(ks + 1, (ks + 1) & 1);
    compute(ks & 1);
    BARRIER_VM();
  }

  // epilogue: C[row=(lane>>4)*4+r][col=lane&15]
  unsigned short* Ls = (unsigned short*)smem;      // bounce [160 n][136 m]
  #pragma unroll
  for (int nt = 0; nt < 5; ++nt) {
    const int n = n0 + wn * 80 + nt * 16 + l15;
    const float bb = bias[n];
    #pragma unroll
    for (int mt = 0; mt < 4; ++mt) {
      #pragma unroll
      for (int r = 0; r < 4; ++r) {
        const int m = m0 + wm * 64 + mt * 16 + lg * 4 + r;
        float v = acc[mt][nt][r] + bb;
        if (mode == 3) {
          const int cm = isDiff ? (m / ND) : ((m - MD) >> 4);
          v -= Xmean[(size_t)cm * DD + n];
        }
        if (ResB) v += b2f(ResB[(size_t)m * DD + n]);
        const unsigned short bv16 = f2b(v);
        OutB[(size_t)m * DD + n] = bv16;
        if (mode == 3) {
          const int nl = wn * 80 + nt * 16 + l15;
          const int ml = wm * 64 + mt * 16 + lg * 4 + r;
          Ls[nl * 136 + ml] = bv16;
        }
      }
    }
  }
  if (mode == 3) {                                 // fused transposed P write
    __syncthreads();
    #pragma unroll
    for (int it = 0; it < 10; ++it) {
      const int flat = it * 256 + t;
      const int nl = flat >> 4, ml = (flat & 15) * 8;
      const int mg = m0 + ml;
      if (isDiff) {
        const int c0c = mg / ND, c1c = (mg + 7) / ND;
        if (c0c == c1c) {
          const i32x4 v = *(const i32x4*)&Ls[nl * 136 + ml];
          *(i32x4*)&PtD[((size_t)c0c * DD + n0 + nl) * 1024 + (mg - c0c * ND)] = v;
        } else {
          #pragma unroll
          for (int j = 0; j < 8; ++j) {
            const int mj = mg + j;
            const int cj = mj / ND;
            PtD[((size_t)cj * DD + n0 + nl) * 1024 + (mj - cj * ND)] = Ls[nl * 136 + ml + j];
          }
        }
      } else {
        const int ls0 = mg - MD;
        const int cj = ls0 >> 4;
        const i32x4 v = *(const i32x4*)&Ls[nl * 136 + ml];
        *(i32x4*)&PtS[((size_t)cj * DD + n0 + nl) * 32 + (ls0 & 15)] = v;
      }
    }
  }
}

// ---------------------------------------------------------------------------
// 16x16 MFMA flash attention, merged regions: blocks [0,1024) diff (XCD
// swizzle, chunk locked 128), blocks [1024,1088) same (direct map).
// 256 thr / 4 waves x 16 q-rows, kv-tile 32, single-buffered staging,
// LDS 40960. Epilogue XOR-swizzled.
// ---------------------------------------------------------------------------
__global__ __launch_bounds__(256, 2) void attn16(
    const unsigned short* __restrict__ Qall, const unsigned short* __restrict__ Pall,
    const unsigned short* __restrict__ PtD, const unsigned short* __restrict__ PtS,
    unsigned short* __restrict__ Oall)
{
  __shared__ __align__(16) char smem[40960];      // staging 40960 | epi 4x10240
  const int t = threadIdx.x;
  const int wid = t >> 6, lane = t & 63;
  const int l15 = lane & 15, lg = lane >> 4;

  int bx = blockIdx.x;
  const unsigned short *Qg, *Pk, *Pt; unsigned short* Ob;
  int cls, blkq, qRows, kPitch, vtPitch, nKT, validKV, qTiles;
  if (bx < 1024) {
    bx = (bx & 7) * 128 + (bx >> 3);              // chunk 128: classes 8x..8x+7 per XCD
    cls = bx >> 4; blkq = bx & 15;
    Qg = Qall; Pk = Pall; Pt = PtD; Ob = Oall;
    qRows = ND; kPitch = ND; vtPitch = 1024; nKT = 32; validKV = ND; qTiles = 63;
  } else {
    cls = bx - 1024; blkq = 0;
    Qg = Qall + (size_t)MD * DD; Pk = Pall + (size_t)MD * DD;
    Pt = PtS; Ob = Oall + (size_t)MD * DD;
    qRows = 16; kPitch = 16; vtPitch = 32; nKT = 1; validKV = 16; qTiles = 1;
  }
  const int qt0 = blkq * 4 + wid;
  const bool wValid = qt0 < qTiles;
  const int qt = wValid ? qt0 : qTiles - 1;

  // Q fragments (B operand): lane holds Q[q=l15][kd = kc*32 + lg*8 + j]
  short8 qf[10];
  {
    const unsigned short* qrow = Qg + ((size_t)cls * qRows + qt * 16 + l15) * DD;
    #pragma unroll
    for (int kc = 0; kc < 10; ++kc) qf[kc] = *(const short8*)(qrow + kc * 32 + lg * 8);
  }

  floatx4 o[20];
  #pragma unroll
  for (int i = 0; i < 20; ++i) o[i] = (floatx4){0.f, 0.f, 0.f, 0.f};
  float mrun = -1e30f, lsum = 0.f;
  const float scale = 0.05590169943749474f;       // 1/sqrt(320)

  for (int kt = 0; kt < nKT; ++kt) {
    // ---- stage K = P rows [32 kv][320 d] and V = P^T [320 d][32 kv] ----
    __syncthreads();
    #pragma unroll
    for (int it = 0; it < 5; ++it) {
      const int L = it * 256 + t;                 // 16B chunk
      const int r = L / 40, c = L - (L / 40) * 40;
      const int cl = (c & ~7) | ((c & 7) ^ (r & 7));
      gl_lds16(Pk + ((size_t)cls * kPitch + kt * 32 + r) * DD + cl * 8, smem + L * 16);
    }
    #pragma unroll
    for (int it = 0; it < 5; ++it) {
      const int L = it * 256 + t;
      const int d = L >> 2, c = L & 3;
      const int cl = c ^ ((d >> 1) & 3);
      gl_lds16(Pt + ((size_t)cls * DD + d) * vtPitch + kt * 32 + cl * 8,
               smem + 20480 + L * 16);
    }
    __syncthreads();

    // ---- S^T = K @ Q^T : lane holds St[kv=st*16+lg*4+r][q=l15] ----
    floatx4 st0 = (floatx4){0.f,0.f,0.f,0.f}, st1 = (floatx4){0.f,0.f,0.f,0.f};
    __builtin_amdgcn_s_setprio(1);
    #pragma unroll
    for (int kc = 0; kc < 10; ++kc) {
      const int c = kc * 4 + lg;
      const int cl = (c & ~7) | ((c & 7) ^ (l15 & 7));
      const short8 k0f = *(const short8*)(smem + l15 * 640 + cl * 16);
      const short8 k1f = *(const short8*)(smem + (16 + l15) * 640 + cl * 16);
      st0 = mfma16(k0f, qf[kc], st0);
      st1 = mfma16(k1f, qf[kc], st1);
    }
    __builtin_amdgcn_s_setprio(0);

    // ---- online softmax ----
    float s[8];
    #pragma unroll
    for (int r = 0; r < 4; ++r) { s[r] = st0[r] * scale; s[4 + r] = st1[r] * scale; }
    const int kvb = kt * 32 + lg * 4;
    #pragma unroll
    for (int r = 0; r < 4; ++r) {
      if (kvb + r      >= validKV) s[r]     = -1e30f;
      if (kvb + 16 + r >= validKV) s[4 + r] = -1e30f;
    }
    float mt_ = s[0];
    #pragma unroll
    for (int i = 1; i < 8; ++i) mt_ = fmaxf(mt_, s[i]);
    mt_ = fmaxf(mt_, __shfl_xor(mt_, 16));
    mt_ = fmaxf(mt_, __shfl_xor(mt_, 32));
    if (!__all(mt_ - mrun <= 8.0f)) {             // T13 defer-max (THR=8)
      const float newm = fmaxf(mrun, mt_);
      const float alpha = __expf(mrun - newm);
      lsum *= alpha;
      #pragma unroll
      for (int i = 0; i < 20; ++i) {
        o[i][0] *= alpha; o[i][1] *= alpha; o[i][2] *= alpha; o[i][3] *= alpha;
      }
      mrun = newm;
    }
    float p[8]; float rs = 0.f;
    #pragma unroll
    for (int i = 0; i < 8; ++i) { p[i] = __expf(s[i] - mrun); rs += p[i]; }
    rs += __shfl_xor(rs, 16);
    rs += __shfl_xor(rs, 32);
    lsum += rs;

    // ---- pack P to bf16, redistribute to PV B-frag ----
    const unsigned int pk00 = pk2(p[0], p[1]), pk01 = pk2(p[2], p[3]);
    const unsigned int pk10 = pk2(p[4], p[5]), pk11 = pk2(p[6], p[7]);
    const int src0 = l15 + ((lane >> 4) & 1) * 32;
    const int src1 = src0 + 16;
    const int y0 = __shfl((int)pk00, src0), y1 = __shfl((int)pk01, src0);
    const int y2 = __shfl((int)pk00, src1), y3 = __shfl((int)pk01, src1);
    const int z0 = __shfl((int)pk10, src0), z1 = __shfl((int)pk11, src0);
    const int z2 = __shfl((int)pk10, src1), z3 = __shfl((int)pk11, src1);
    const bool hi = lane >= 32;                   // subtile select (kv>=16)
    union { i32x4 w; short8 v; } pf;
    pf.w[0] = hi ? z0 : y0; pf.w[1] = hi ? z1 : y1;
    pf.w[2] = hi ? z2 : y2; pf.w[3] = hi ? z3 : y3;

    // ---- O^T += Pt_tile @ P : 20 d-tiles ----
    const int vswz = (l15 >> 1) & 3;
    __builtin_amdgcn_s_setprio(1);
    #pragma unroll
    for (int dt = 0; dt < 20; ++dt) {
      const int d = dt * 16 + l15;
      const short8 a = *(const short8*)(smem + 20480 + d * 64 + ((lg ^ vswz) << 4));
      o[dt] = mfma16(a, pf.v, o[dt]);
    }
    __builtin_amdgcn_s_setprio(0);
  }

  // ---- epilogue: per-wave LDS [16q][pitch 640B], XOR-swizzled (2-way max) ----
  const float invl = 1.f / lsum;
  __syncthreads();
  char* ep = smem + wid * 10240;
  const int qx = (l15 & 7) << 4;
  #pragma unroll
  for (int dt = 0; dt < 20; ++dt) {
    const unsigned int w0 = pk2(o[dt][0] * invl, o[dt][1] * invl);
    const unsigned int w1 = pk2(o[dt][2] * invl, o[dt][3] * invl);
    *(unsigned int*)(ep + l15 * 640 + (((dt * 16 + lg * 4) * 2) ^ qx))     = w0;
    *(unsigned int*)(ep + l15 * 640 + (((dt * 16 + lg * 4 + 2) * 2) ^ qx)) = w1;
  }
  __syncthreads();
  if (wValid) {
    #pragma unroll
    for (int it = 0; it < 10; ++it) {
      const int flat = it * 64 + lane;
      const int q = flat / 40, c = flat - (flat / 40) * 40;
      const i32x4 v = *(const i32x4*)(ep + q * 640 + ((c * 16) ^ ((q & 7) << 4)));
      *(i32x4*)(Ob + ((size_t)cls * qRows + qt * 16 + q) * DD + c * 8) = v;
    }
  }
}

// ---------------------------------------------------------------------------
// Merged weight prep (grid.z selects task):
//  z=0: BtS = (Wsame)^T bf16   z=1: BtD = (Wdiff)^T bf16
//  z=2: BtG[n][k] = sum_m Wk[n,m] Wq[k,m]   z=3: BtVF[n][k] = sum_m Wfc[m,n] Wv[k,m]
//  z=4 (x==0): vbias[n] = Wk[n,:].bq ; bvf[n] = Wfc[:,n].bv + bfc[n]
// ---------------------------------------------------------------------------
__global__ __launch_bounds__(256) void wprep(
    const float* __restrict__ Wsame, const float* __restrict__ Wdiff,
    const float* __restrict__ Wk, const float* __restrict__ Wq,
    const float* __restrict__ Wfc, const float* __restrict__ Wv,
    const float* __restrict__ bq, const float* __restrict__ bv,
    const float* __restrict__ bfc,
    unsigned short* __restrict__ BtS, unsigned short* __restrict__ BtD,
    unsigned short* __restrict__ BtG, unsigned short* __restrict__ BtVF,
    float* __restrict__ vbias, float* __restrict__ bvf)
{
  __shared__ float Ls[64 * 68];
  const int t = threadIdx.x;
  const int z = blockIdx.z;
  if (z < 2) {                                   // transpose fp32 -> bf16^T
    const float* W = z ? Wdiff : Wsame;
    unsigned short* Wt = z ? BtD : BtS;
    const int k0 = blockIdx.x * 64, n0 = blockIdx.y * 64;
    #pragma unroll
    for (int i = 0; i < 4; ++i) {
      const int flat = t + i * 256;
      const int r = flat >> 4, c = (flat & 15) * 4;
      *(float4*)&Ls[r * 68 + c] = *(const float4*)(W + (size_t)(k0 + r) * DD + n0 + c);
    }
    __syncthreads();
    #pragma unroll
    for (int j = 0; j < 2; ++j) {
      const int flat = t + j * 256;
      const int r2 = flat >> 3, c2 = flat & 7;
      union { unsigned short e[8]; i32x4 v; } u;
      #pragma unroll
      for (int jj = 0; jj < 8; ++jj) u.e[jj] = f2b(Ls[(c2 * 8 + jj) * 68 + r2]);
      *(i32x4*)(Wt + (size_t)(n0 + r2) * DD + k0 + c2 * 8) = u.v;
    }
  } else if (z < 4) {                            // weight product
    const int trL = (z == 3);
    const float* L = trL ? Wfc : Wk;
    const float* R = trL ? Wv : Wq;
    float* Lsm = Ls;                // [16][68]
    float* Rsm = Ls + 16 * 68;
    const int n0 = blockIdx.x * 64, k0 = blockIdx.y * 64;
    const int tn4 = (t & 15) * 4, tk4 = (t >> 4) * 4;
    float acc[4][4] = {};
    for (int ms = 0; ms < DD; ms += 16) {
      const int lr = t >> 4, lc = (t & 15);
      #pragma unroll
      for (int i = 0; i < 4; ++i) {
        const int nn = lc * 4 + i;
        Lsm[lr * 68 + nn] = trL ? L[(size_t)(ms + lr) * DD + n0 + nn]
                                : L[(size_t)(n0 + nn) * DD + ms + lr];
        Rsm[lr * 68 + nn] = R[(size_t)(k0 + nn) * DD + ms + lr];
      }
      __syncthreads();
      #pragma unroll
      for (int mm = 0; mm < 16; ++mm) {
        float la[4], rb[4];
        #pragma unroll
        for (int i = 0; i < 4; ++i) { la[i] = Lsm[mm * 68 + tn4 + i]; rb[i] = Rsm[mm * 68 + tk4 + i]; }
        #pragma unroll
        for (int i = 0; i < 4; ++i)
          #pragma unroll
          for (int j = 0; j < 4; ++j) acc[i][j] += la[i] * rb[j];
      }
      __syncthreads();
    }
    #pragma unroll
    for (int i = 0; i < 4; ++i)
      #pragma unroll
      for (int j = 0; j < 4; ++j)
        ((z == 2) ? BtG : BtVF)[(size_t)(n0 + tn4 + i) * DD + k0 + tk4 + j] = f2b(acc[i][j]);
  } else {                                       // z == 4: folded biases
    if (blockIdx.x == 0) {
      const int n0 = blockIdx.y * 64;
      if (t < 64) {
        const int n = n0 + t;
        float a = 0.f;
        for (int m = 0; m < DD; ++m) a += Wk[(size_t)n * DD + m] * bq[m];
        vbias[n] = a;
      } else if (t < 128) {
        const int n = n0 + t - 64;
        float a = 0.f;
        for (int m = 0; m < DD; ++m) a += Wfc[(size_t)m * DD + n] * bv[m];
        bvf[n] = a + bfc[n];
      }
    }
  }
}

// ---------------------------------------------------------------------------
// Per-row LayerNorm + logit (bf16 in), 1 wave/row, merged M=65536.
// ---------------------------------------------------------------------------
__global__ __launch_bounds__(256) void ln_logit(
    const unsigned short* __restrict__ X, const float* __restrict__ gam,
    const float* __restrict__ bet, const float* __restrict__ Wout,
    const float* __restrict__ bout, float* __restrict__ logits, const int M)
{
  const int row = blockIdx.x * 4 + (threadIdx.x >> 6);
  if (row >= M) return;
  const int lane = threadIdx.x & 63;
  const unsigned short* x = X + (size_t)row * DD;
  float v[5]; float s = 0.f;
  #pragma unroll
  for (int i = 0; i < 5; ++i) { v[i] = b2f(x[lane + 64 * i]); s += v[i]; }
  #pragma unroll
  for (int off = 32; off; off >>= 1) s += __shfl_xor(s, off);
  const float mu = s * (1.f / DD);
  float q = 0.f;
  #pragma unroll
  for (int i = 0; i < 5; ++i) { const float d = v[i] - mu; q += d * d; }
  #pragma unroll
  for (int off = 32; off; off >>= 1) q += __shfl_xor(q, off);
  const float inv = rsqrtf(q * (1.f / DD) + LN_EPS);
  float lg = 0.f;
  #pragma unroll
  for (int i = 0; i < 5; ++i) {
    const int k = lane + 64 * i;
    lg += (gam[k] * (v[i] - mu) * inv + bet[k]) * Wout[k];
  }
  #pragma unroll
  for (int off = 32; off; off >>= 1) lg += __shfl_xor(lg, off);
  if (lane == 0) logits[row] = lg + bout[0];
}

// ---------------------------------------------------------------------------
// Final: per-class softmax over logits, weighted mean of P (bf16).
// grid (CC, 5): each block handles one 64-column d-slice of one class.
// ---------------------------------------------------------------------------
__global__ __launch_bounds__(320) void final_reduce(
    const float* __restrict__ logits_s, const float* __restrict__ logits_d,
    const unsigned short* __restrict__ Ps, const unsigned short* __restrict__ Pd,
    float* __restrict__ out)
{
  const int c = blockIdx.x;
  const int dt = blockIdx.y;
  const int t = threadIdx.x;
  __shared__ float w[16 + ND];
  __shared__ float red[5];
  __shared__ float accs[5][64];
  if (t < 16) w[t] = logits_s[c * 16 + t];
  for (int j = t; j < ND; j += 320) w[16 + j] = logits_d[c * ND + j];
  __syncthreads();
  if (t == 0) {
    float mx = w[0];
    #pragma unroll
    for (int i = 1; i < 16; ++i) mx = fmaxf(mx, w[i]);
    float ssum = 0.f;
    #pragma unroll
    for (int i = 0; i < 16; ++i) { const float e = __expf(w[i] - mx); w[i] = e; ssum += e; }
    const float inv = 1.f / ssum;
    #pragma unroll
    for (int i = 0; i < 16; ++i) w[i] *= inv;
  }
  float lm = -1e30f;
  for (int j = t; j < ND; j += 320) lm = fmaxf(lm, w[16 + j]);
  #pragma unroll
  for (int off = 32; off; off >>= 1) lm = fmaxf(lm, __shfl_xor(lm, off));
  if ((t & 63) == 0) red[t >> 6] = lm;
  __syncthreads();
  const float mx = fmaxf(fmaxf(fmaxf(red[0], red[1]), fmaxf(red[2], red[3])), red[4]);
  float ls = 0.f;
  for (int j = t; j < ND; j += 320) { const float e = __expf(w[16 + j] - mx); w[16 + j] = e; ls += e; }
  #pragma unroll
  for (int off = 32; off; off >>= 1) ls += __shfl_xor(ls, off);
  __syncthreads();
  if ((t & 63) == 0) red[t >> 6] = ls;
  __syncthreads();
  const float inv = 1.f / (red[0] + red[1] + red[2] + red[3] + red[4]);
  for (int j = t; j < ND; j += 320) w[16 + j] *= inv;
  __syncthreads();
  const int col = dt * 64 + (t & 63);
  const int jg  = t >> 6;                        // 0..4
  float acc = 0.f;
  const unsigned short* Psc = Ps + (size_t)c * SHOT * DD + col;
  const unsigned short* Pdc = Pd + (size_t)c * ND * DD + col;
  if (jg == 0) {
    #pragma unroll
    for (int i = 0; i < 16; ++i) acc += w[i] * b2f(Psc[(size_t)i * DD]);
  }
  for (int j = jg; j < ND; j += 5) acc += w[16 + j] * b2f(Pdc[(size_t)j * DD]);
  accs[jg][t & 63] = acc;
  __syncthreads();
  if (t < 64)
    out[c * DD + dt * 64 + t] =
        (accs[0][t] + accs[1][t] + accs[2][t] + accs[3][t] + accs[4][t]) * (1.f / 1024.f);
}

// ---------------------------------------------------------------------------
extern "C" void kernel_launch(void* const* d_in, const int* in_sizes, int n_in,
                              void* d_out, int out_size, void* d_ws, size_t ws_size,
                              hipStream_t stream)
{
  const float* xmean = (const float*)d_in[0];
  const float* x     = (const float*)d_in[1];
  const float* Wsame = (const float*)d_in[2];
  const float* bsame = (const float*)d_in[3];
  const float* Wdiff = (const float*)d_in[4];
  const float* bdiff = (const float*)d_in[5];
  const float* Wq    = (const float*)d_in[6];
  const float* bq    = (const float*)d_in[7];
  const float* Wk    = (const float*)d_in[8];
  const float* bk    = (const float*)d_in[9];   (void)bk; // row-const in softmax
  const float* Wv    = (const float*)d_in[10];
  const float* bv    = (const float*)d_in[11];
  const float* Wfc   = (const float*)d_in[12];
  const float* bfc   = (const float*)d_in[13];
  const float* lng   = (const float*)d_in[14];
  const float* lnb   = (const float*)d_in[15];
  const float* Wout  = (const float*)d_in[16];
  const float* boutp = (const float*)d_in[17];
  float* outp = (float*)d_out;

  char* base = (char*)d_ws;
  size_t off = 0;
  auto alloc = [&](size_t bytes) { char* p = base + off; off += (bytes + 255) & ~(size_t)255; return p; };

  const size_t WB = (size_t)DD * DD * 2;
  unsigned short* BtS  = (unsigned short*)alloc(WB);
  unsigned short* BtD  = (unsigned short*)alloc(WB);
  unsigned short* BtG  = (unsigned short*)alloc(WB);
  unsigned short* BtVF = (unsigned short*)alloc(WB);
  float* vbias = (float*)alloc(DD * 4);
  float* bvf   = (float*)alloc(DD * 4);
  // merged row space: [0,MD) diff (per class 1008), [MD,MT) same (per class 16)
  unsigned short* P_b  = (unsigned short*)alloc((size_t)MT * DD * 2);
  unsigned short* Qg_b = (unsigned short*)alloc((size_t)MT * DD * 2);  // also F out
  unsigned short* O_b  = (unsigned short*)alloc((size_t)MT * DD * 2);
  unsigned short* PtD  = (unsigned short*)alloc((size_t)CC * DD * 1024 * 2);
  unsigned short* PtS  = (unsigned short*)alloc((size_t)CC * DD * 32 * 2);
  float* logits = (float*)alloc((size_t)MT * 4);

  const dim3 blk(256);
  // ---- weight prep ----
  wprep<<<dim3(5, 5, 5), blk, 0, stream>>>(Wsame, Wdiff, Wk, Wq, Wfc, Wv,
                                           bq, bv, bfc,
                                           BtS, BtD, BtG, BtVF, vbias, bvf);

  // ---- P (+fused P^T), both branches, one dispatch ----
  const dim3 gAll(MT / 128, 2);
  gemm_mfma<<<gAll, blk, 0, stream>>>(nullptr, x, xmean, 3, BtD, BtS,
                                      bdiff, bsame, P_b, nullptr, PtD, PtS);
  // ---- Qg = P @ G + vbias (merged) ----
  gemm_mfma<<<gAll, blk, 0, stream>>>(P_b, nullptr, nullptr, 0, BtG, nullptr,
                                      vbias, nullptr, Qg_b, nullptr, nullptr, nullptr);
  // ---- attention (diff + same, one dispatch) ----
  attn16<<<dim3(1088), blk, 0, stream>>>(Qg_b, P_b, PtD, PtS, O_b);
  // ---- F = O @ (Wv Wfc) + bvf + P (merged) ----
  gemm_mfma<<<gAll, blk, 0, stream>>>(O_b, nullptr, nullptr, 0, BtVF, nullptr,
                                      bvf, nullptr, Qg_b, P_b, nullptr, nullptr);
  // ---- LN + logits (merged) ----
  ln_logit<<<dim3(MT / 4), blk, 0, stream>>>(Qg_b, lng, lnb, Wout, boutp, logits, MT);
  // ---- final softmax-weighted mean (parallel over 5 d-slices) ----
  final_reduce<<<dim3(CC, 5), dim3(320), 0, stream>>>(logits + MD, logits,
                                                      P_b + (size_t)MD * DD, P_b, outp);
}